// Round 1
// baseline (465.332 us; speedup 1.0000x reference)
//
#include <hip/hip_runtime.h>

typedef unsigned short u16;
typedef __attribute__((ext_vector_type(8))) short short8;
typedef __attribute__((ext_vector_type(4))) float f32x4;

#define MFMA16(a, b, c) __builtin_amdgcn_mfma_f32_16x16x32_bf16((a), (b), (c), 0, 0, 0)

__device__ __forceinline__ u16 f2bf(float f) {
    unsigned u = __float_as_uint(f);
    unsigned r = (u + 0x7FFFu + ((u >> 16) & 1u)) >> 16;
    return (u16)r;
}

__device__ const float MAXV[22] = {9.f, 1.f, 1.f, 10.f, 3.f, 254.f, 1.f, 1.f, 235.f, 8.f, 9.f,
                                   250.f, 29.f, 1.f, 1.f, 8.f, 1.f, 1.f, 6.f, 3.f, 1.f, 2.f};

// ---------------- prep: weights -> bf16, transposed [N][K], 1/MAX folded ----------------
__global__ void prep_kernel(
    const float* c1w, const float* c1b, const float* c2w, const float* c2b,
    const float* fcw, const float* fcb, const float* sfw, const float* sfb,
    const float* a0w, const float* a0b, const float* a1w, const float* a1b,
    const float* vw, const float* vb,
    u16* W1T, u16* W2T, u16* FCT, u16* SELFT, u16* HEADW, float* BIAS)
{
    int idx = blockIdx.x * 256 + threadIdx.x;
    if (idx < 73728) {                       // W1T [128][576]: k = c*25 + kx*5 + ky
        int n = idx / 576, k = idx - n * 576;
        float v = 0.f;
        if (k < 550) { int c = k / 25; v = c1w[n * 550 + k] * (1.0f / MAXV[c]); }
        W1T[idx] = f2bf(v);
    } else if (idx < 221184) {               // W2T [128][1152]: k = p*128 + ic
        int j = idx - 73728;
        int oc = j / 1152, k = j - oc * 1152;
        int p = k >> 7, ic = k & 127;
        W2T[j] = f2bf(c2w[oc * 1152 + ic * 9 + p]);
    } else if (idx < 253952) {               // FCT [256][128]
        int j = idx - 221184;
        FCT[j] = f2bf(fcw[j]);
    } else if (idx < 262144) {               // SELFT [256][32] (k pad 22->32)
        int j = idx - 253952;
        int n = j >> 5, c = j & 31;
        float v = (c < 22) ? sfw[n * 22 + c] * (1.0f / MAXV[c]) : 0.f;
        SELFT[j] = f2bf(v);
    } else if (idx < 278528) {               // HEADW [32][512]: rows 0-8 a0, 9-18 a1, 19 value
        int j = idx - 262144;
        int n = j >> 9, k = j & 511;
        float v = 0.f;
        if (n < 9) v = a0w[n * 512 + k];
        else if (n < 19) v = a1w[(n - 9) * 512 + k];
        else if (n == 19) v = vw[k];
        HEADW[j] = f2bf(v);
    } else if (idx < 279328) {               // BIAS[800]: c1(128) c2(128) fc(256) self(256) heads(32)
        int j = idx - 278528;
        float v = 0.f;
        if (j < 128) v = c1b[j];
        else if (j < 256) v = c2b[j - 128];
        else if (j < 512) v = fcb[j - 256];
        else if (j < 768) v = sfb[j - 512];
        else {
            int j2 = j - 768;
            if (j2 < 9) v = a0b[j2]; else if (j2 < 19) v = a1b[j2 - 9]; else if (j2 == 19) v = vb[0];
        }
        BIAS[j] = v;
    }
}

// ---------------- K12: scatter+dedupe -> im2col in LDS -> conv1 GEMM -> h1 ----------------
// 8 samples/WG. A_lds [80 rows][584] bf16 (72 real rows = 8 samples x 9 positions, stride-pad
// 584 -> bank step 4 -> 2-way conflict (free)). box: int-encoded (m<<8|val) atomicMax dedupe.
__global__ __launch_bounds__(256) void k12_kernel(
    const int* __restrict__ obs, const u16* __restrict__ W1T,
    const float* __restrict__ BIAS, u16* __restrict__ h1, u16* __restrict__ s22g)
{
    __shared__ u16 A[80 * 584];      // 93,440 B
    __shared__ u16 Bt[128 * 72];     // 18,432 B
    __shared__ int box[2 * 2662];    // 21,296 B
    __shared__ u16 s22[8 * 32];      //    512 B
    const int tid = threadIdx.x, w = tid >> 6, l = tid & 63;
    const int s0 = blockIdx.x * 8;

    {
        short8 z = {0, 0, 0, 0, 0, 0, 0, 0};
        for (int i = tid; i < (80 * 584) / 8; i += 256) *(short8*)(A + i * 8) = z;
        s22[tid] = 0;
    }
    for (int pair = 0; pair < 4; ++pair) {
        __syncthreads();
        for (int i = tid; i < 5324; i += 256) box[i] = 0;
        __syncthreads();
        for (int i = tid; i < 400; i += 256) {
            int sub = (i >= 200);
            int m = i - sub * 200;
            const int* tp = obs + ((long)(s0 + pair * 2 + sub) * 200 + m) * 3;
            int c = tp[0], a = tp[1], v = tp[2];
            c = (c == 255) ? 0 : c; a = (a == 255) ? 0 : a; v = (v == 255) ? 0 : v;
            int xs = (c >> 4) & 15, ys = c & 15;
            if ((unsigned)a < 22u && xs < 11 && ys < 11)
                atomicMax(&box[sub * 2662 + a * 121 + xs * 11 + ys], (m << 8) | (v & 255));
        }
        __syncthreads();
        for (int i = tid; i < 5324; i += 256) {
            int enc = box[i];
            if (enc == 0) continue;
            int sub = (i >= 2662);
            int ci = i - sub * 2662;
            int c = ci / 121; int g = ci - c * 121;
            int gx = g / 11;  int gy = g - gx * 11;
            int ls = pair * 2 + sub;
            u16 bv = f2bf((float)(enc & 255));
            if (gx == 5 && gy == 5) s22[ls * 32 + c] = bv;
            int bcol = c * 25;
            for (int ox = 0; ox < 3; ++ox) {
                int kx = gx - 3 * ox;
                if ((unsigned)kx > 4u) continue;
                for (int oy = 0; oy < 3; ++oy) {
                    int ky = gy - 3 * oy;
                    if ((unsigned)ky > 4u) continue;
                    A[(ls * 9 + ox * 3 + oy) * 584 + bcol + kx * 5 + ky] = bv;
                }
            }
        }
    }
    __syncthreads();
    s22g[s0 * 32 + tid] = s22[tid];

    // GEMM [80 x 576] x [576 x 128]; wave w owns 32 cols, 5 M-tiles of 16.
    f32x4 acc[5][2];
    const f32x4 fz = {0.f, 0.f, 0.f, 0.f};
    for (int i = 0; i < 5; ++i) { acc[i][0] = fz; acc[i][1] = fz; }
    for (int kc = 0; kc < 9; ++kc) {
        __syncthreads();
        for (int s = tid; s < 1024; s += 256) {
            int n = s >> 3, seg = s & 7;
            *(short8*)(Bt + n * 72 + seg * 8) = *(const short8*)(W1T + n * 576 + kc * 64 + seg * 8);
        }
        __syncthreads();
        const int colw = w * 32;
        #pragma unroll
        for (int ks = 0; ks < 2; ++ks) {
            short8 b0 = *(short8*)(Bt + (colw + (l & 15)) * 72 + ks * 32 + ((l >> 4) << 3));
            short8 b1 = *(short8*)(Bt + (colw + 16 + (l & 15)) * 72 + ks * 32 + ((l >> 4) << 3));
            #pragma unroll
            for (int mt = 0; mt < 5; ++mt) {
                short8 a = *(short8*)(A + (mt * 16 + (l & 15)) * 584 + kc * 64 + ks * 32 + ((l >> 4) << 3));
                acc[mt][0] = MFMA16(a, b0, acc[mt][0]);
                acc[mt][1] = MFMA16(a, b1, acc[mt][1]);
            }
        }
    }
    const long h1base = (long)blockIdx.x * 72 * 128;
    #pragma unroll
    for (int mt = 0; mt < 5; ++mt) {
        #pragma unroll
        for (int nt = 0; nt < 2; ++nt) {
            int col = w * 32 + nt * 16 + (l & 15);
            float bias = BIAS[col];
            #pragma unroll
            for (int r = 0; r < 4; ++r) {
                int row = mt * 16 + ((l >> 4) << 2) + r;
                if (row < 72) {
                    float v = acc[mt][nt][r] + bias;
                    v = v > 0.f ? v : 0.f;
                    h1[h1base + (long)row * 128 + col] = f2bf(v);
                }
            }
        }
    }
}

// ---------------- K3: conv2 + fc + self + heads, 64 samples/WG ----------------
__global__ __launch_bounds__(256) void k3_kernel(
    const u16* __restrict__ h1, const u16* __restrict__ s22g,
    const u16* __restrict__ W2T, const u16* __restrict__ FCT,
    const u16* __restrict__ SELFT, const u16* __restrict__ HEADW,
    const float* __restrict__ BIAS, float* __restrict__ out, int B)
{
    __shared__ u16 A3[64 * 136];     // conv2 out (relu, bf16), stride-pad 136
    __shared__ u16 HID[64 * 520];    // hidden [64][512], stride-pad 520
    __shared__ u16 Ab[64 * 72];
    __shared__ u16 Bb[256 * 72];
    const int tid = threadIdx.x, w = tid >> 6, l = tid & 63;
    const int s0 = blockIdx.x * 64;
    const float* c2b = BIAS + 128;
    const float* fcb = BIAS + 256;
    const float* sfb = BIAS + 512;
    const float* hdb = BIAS + 768;
    const f32x4 fz = {0.f, 0.f, 0.f, 0.f};

    f32x4 acc[4][4];

    // ---- conv2: [64,1152] @ W2T[128][1152] ----
    for (int i = 0; i < 4; ++i) { acc[i][0] = fz; acc[i][1] = fz; }
    for (int kc = 0; kc < 18; ++kc) {
        __syncthreads();
        for (int s = tid; s < 512; s += 256) {
            int r = s >> 3, seg = s & 7;
            *(short8*)(Ab + r * 72 + seg * 8) = *(const short8*)(h1 + (long)(s0 + r) * 1152 + kc * 64 + seg * 8);
        }
        for (int s = tid; s < 1024; s += 256) {
            int n = s >> 3, seg = s & 7;
            *(short8*)(Bb + n * 72 + seg * 8) = *(const short8*)(W2T + n * 1152 + kc * 64 + seg * 8);
        }
        __syncthreads();
        const int colw = w * 32;
        #pragma unroll
        for (int ks = 0; ks < 2; ++ks) {
            short8 b0 = *(short8*)(Bb + (colw + (l & 15)) * 72 + ks * 32 + ((l >> 4) << 3));
            short8 b1 = *(short8*)(Bb + (colw + 16 + (l & 15)) * 72 + ks * 32 + ((l >> 4) << 3));
            #pragma unroll
            for (int mt = 0; mt < 4; ++mt) {
                short8 a = *(short8*)(Ab + (mt * 16 + (l & 15)) * 72 + ks * 32 + ((l >> 4) << 3));
                acc[mt][0] = MFMA16(a, b0, acc[mt][0]);
                acc[mt][1] = MFMA16(a, b1, acc[mt][1]);
            }
        }
    }
    {
        const int colw = w * 32;
        #pragma unroll
        for (int mt = 0; mt < 4; ++mt)
            #pragma unroll
            for (int nt = 0; nt < 2; ++nt) {
                int col = colw + nt * 16 + (l & 15);
                float bias = c2b[col];
                #pragma unroll
                for (int r = 0; r < 4; ++r) {
                    int row = mt * 16 + ((l >> 4) << 2) + r;
                    float v = acc[mt][nt][r] + bias; v = v > 0.f ? v : 0.f;
                    A3[row * 136 + col] = f2bf(v);
                }
            }
    }
    __syncthreads();

    // ---- fc: A3[64][128] @ FCT[256][128] -> HID cols 256..511 ----
    for (int i = 0; i < 4; ++i) for (int j = 0; j < 4; ++j) acc[i][j] = fz;
    for (int kc = 0; kc < 2; ++kc) {
        __syncthreads();
        for (int s = tid; s < 2048; s += 256) {
            int n = s >> 3, seg = s & 7;
            *(short8*)(Bb + n * 72 + seg * 8) = *(const short8*)(FCT + n * 128 + kc * 64 + seg * 8);
        }
        __syncthreads();
        const int colw = w * 64;
        #pragma unroll
        for (int ks = 0; ks < 2; ++ks) {
            short8 b[4];
            #pragma unroll
            for (int nt = 0; nt < 4; ++nt)
                b[nt] = *(short8*)(Bb + (colw + nt * 16 + (l & 15)) * 72 + ks * 32 + ((l >> 4) << 3));
            #pragma unroll
            for (int mt = 0; mt < 4; ++mt) {
                short8 a = *(short8*)(A3 + (mt * 16 + (l & 15)) * 136 + kc * 64 + ks * 32 + ((l >> 4) << 3));
                #pragma unroll
                for (int nt = 0; nt < 4; ++nt) acc[mt][nt] = MFMA16(a, b[nt], acc[mt][nt]);
            }
        }
    }
    {
        const int colw = w * 64;
        #pragma unroll
        for (int mt = 0; mt < 4; ++mt)
            #pragma unroll
            for (int nt = 0; nt < 4; ++nt) {
                int col = colw + nt * 16 + (l & 15);
                float bias = fcb[col];
                #pragma unroll
                for (int r = 0; r < 4; ++r) {
                    int row = mt * 16 + ((l >> 4) << 2) + r;
                    float v = acc[mt][nt][r] + bias; v = v > 0.f ? v : 0.f;
                    HID[row * 520 + 256 + col] = f2bf(v);
                }
            }
    }
    __syncthreads();

    // ---- self: s22[64][32] @ SELFT[256][32] -> HID cols 0..255 ----
    for (int i = 0; i < 4; ++i) for (int j = 0; j < 4; ++j) acc[i][j] = fz;
    for (int s = tid; s < 256; s += 256) {
        int r = s >> 2, seg = s & 3;
        *(short8*)(Ab + r * 72 + seg * 8) = *(const short8*)(s22g + (s0 + r) * 32 + seg * 8);
    }
    for (int s = tid; s < 1024; s += 256) {
        int n = s >> 2, seg = s & 3;
        *(short8*)(Bb + n * 72 + seg * 8) = *(const short8*)(SELFT + n * 32 + seg * 8);
    }
    __syncthreads();
    {
        const int colw = w * 64;
        short8 b[4];
        #pragma unroll
        for (int nt = 0; nt < 4; ++nt)
            b[nt] = *(short8*)(Bb + (colw + nt * 16 + (l & 15)) * 72 + ((l >> 4) << 3));
        #pragma unroll
        for (int mt = 0; mt < 4; ++mt) {
            short8 a = *(short8*)(Ab + (mt * 16 + (l & 15)) * 72 + ((l >> 4) << 3));
            #pragma unroll
            for (int nt = 0; nt < 4; ++nt) acc[mt][nt] = MFMA16(a, b[nt], acc[mt][nt]);
        }
        #pragma unroll
        for (int mt = 0; mt < 4; ++mt)
            #pragma unroll
            for (int nt = 0; nt < 4; ++nt) {
                int col = colw + nt * 16 + (l & 15);
                float bias = sfb[col];
                #pragma unroll
                for (int r = 0; r < 4; ++r) {
                    int row = mt * 16 + ((l >> 4) << 2) + r;
                    float v = acc[mt][nt][r] + bias; v = v > 0.f ? v : 0.f;
                    HID[row * 520 + col] = f2bf(v);
                }
            }
    }

    // ---- heads: HID[64][512] @ HEADW[32][512]; wave w owns rows w*16..w*16+15 ----
    f32x4 hacc[2]; hacc[0] = fz; hacc[1] = fz;
    for (int kc = 0; kc < 8; ++kc) {
        __syncthreads();
        for (int s = tid; s < 256; s += 256) {
            int r = s >> 3, seg = s & 7;
            *(short8*)(Bb + r * 72 + seg * 8) = *(const short8*)(HEADW + r * 512 + kc * 64 + seg * 8);
        }
        __syncthreads();
        #pragma unroll
        for (int ks = 0; ks < 2; ++ks) {
            short8 a  = *(short8*)(HID + (w * 16 + (l & 15)) * 520 + kc * 64 + ks * 32 + ((l >> 4) << 3));
            short8 b0 = *(short8*)(Bb + ((l & 15)) * 72 + ks * 32 + ((l >> 4) << 3));
            short8 b1 = *(short8*)(Bb + (16 + (l & 15)) * 72 + ks * 32 + ((l >> 4) << 3));
            hacc[0] = MFMA16(a, b0, hacc[0]);
            hacc[1] = MFMA16(a, b1, hacc[1]);
        }
    }
    #pragma unroll
    for (int nt = 0; nt < 2; ++nt) {
        #pragma unroll
        for (int r = 0; r < 4; ++r) {
            int srow = s0 + w * 16 + ((l >> 4) << 2) + r;
            int col = nt * 16 + (l & 15);
            float v = hacc[nt][r] + hdb[col];
            if (col < 9) out[(long)srow * 9 + col] = v;
            else if (col < 19) out[(long)B * 9 + (long)srow * 10 + (col - 9)] = v;
            else if (col == 19) out[(long)B * 19 + srow] = v;
        }
    }
}

extern "C" void kernel_launch(void* const* d_in, const int* in_sizes, int n_in,
                              void* d_out, int out_size, void* d_ws, size_t ws_size,
                              hipStream_t stream)
{
    const int*   obs = (const int*)d_in[0];
    const float* c1w = (const float*)d_in[1];
    const float* c1b = (const float*)d_in[2];
    const float* c2w = (const float*)d_in[3];
    const float* c2b = (const float*)d_in[4];
    const float* fcw = (const float*)d_in[5];
    const float* fcb = (const float*)d_in[6];
    const float* sfw = (const float*)d_in[7];
    const float* sfb = (const float*)d_in[8];
    const float* a0w = (const float*)d_in[9];
    const float* a0b = (const float*)d_in[10];
    const float* a1w = (const float*)d_in[11];
    const float* a1b = (const float*)d_in[12];
    const float* vw  = (const float*)d_in[13];
    const float* vb  = (const float*)d_in[14];
    const int B = in_sizes[0] / 600;   // 16384

    char* ws = (char*)d_ws;
    u16*   W1T   = (u16*)(ws + 0);
    u16*   W2T   = (u16*)(ws + 147456);
    u16*   FCT   = (u16*)(ws + 442368);
    u16*   SELFT = (u16*)(ws + 507904);
    u16*   HEADW = (u16*)(ws + 524288);
    float* BIAS  = (float*)(ws + 557056);
    u16*   s22g  = (u16*)(ws + 560256);
    u16*   h1    = (u16*)(ws + 560256 + (size_t)B * 64);

    prep_kernel<<<1092, 256, 0, stream>>>(c1w, c1b, c2w, c2b, fcw, fcb, sfw, sfb,
                                          a0w, a0b, a1w, a1b, vw, vb,
                                          W1T, W2T, FCT, SELFT, HEADW, BIAS);
    k12_kernel<<<B / 8, 256, 0, stream>>>(obs, W1T, BIAS, h1, s22g);
    k3_kernel<<<B / 64, 256, 0, stream>>>(h1, s22g, W2T, FCT, SELFT, HEADW, BIAS,
                                          (float*)d_out, B);
}

// Round 2
// 136.127 us; speedup vs baseline: 3.4184x; 3.4184x over previous
//
#include <hip/hip_runtime.h>

typedef unsigned short u16;
typedef __attribute__((ext_vector_type(8))) short short8;
typedef __attribute__((ext_vector_type(4))) float f32x4;

#define MFMA16(a, b, c) __builtin_amdgcn_mfma_f32_16x16x32_bf16((a), (b), (c), 0, 0, 0)

__device__ __forceinline__ u16 f2bf(float f) {
    unsigned u = __float_as_uint(f);
    unsigned r = (u + 0x7FFFu + ((u >> 16) & 1u)) >> 16;
    return (u16)r;
}

__device__ const float MAXV[22] = {9.f, 1.f, 1.f, 10.f, 3.f, 254.f, 1.f, 1.f, 235.f, 8.f, 9.f,
                                   250.f, 29.f, 1.f, 1.f, 8.f, 1.f, 1.f, 6.f, 3.f, 1.f, 2.f};

// ---------------- prep: weights -> bf16, transposed [N][K], 1/MAX folded ----------------
__global__ void prep_kernel(
    const float* c1w, const float* c1b, const float* c2w, const float* c2b,
    const float* fcw, const float* fcb, const float* sfw, const float* sfb,
    const float* a0w, const float* a0b, const float* a1w, const float* a1b,
    const float* vw, const float* vb,
    u16* W1T, u16* W2T, u16* FCT, u16* SELFT, u16* HEADW, float* BIAS)
{
    int idx = blockIdx.x * 256 + threadIdx.x;
    if (idx < 73728) {                       // W1T [128][576]: k = c*25 + kx*5 + ky
        int n = idx / 576, k = idx - n * 576;
        float v = 0.f;
        if (k < 550) { int c = k / 25; v = c1w[n * 550 + k] * (1.0f / MAXV[c]); }
        W1T[idx] = f2bf(v);
    } else if (idx < 221184) {               // W2T [128][1152]: k = p*128 + ic
        int j = idx - 73728;
        int oc = j / 1152, k = j - oc * 1152;
        int p = k >> 7, ic = k & 127;
        W2T[j] = f2bf(c2w[oc * 1152 + ic * 9 + p]);
    } else if (idx < 253952) {               // FCT [256][128]
        int j = idx - 221184;
        FCT[j] = f2bf(fcw[j]);
    } else if (idx < 262144) {               // SELFT [256][32] (k pad 22->32)
        int j = idx - 253952;
        int n = j >> 5, c = j & 31;
        float v = (c < 22) ? sfw[n * 22 + c] * (1.0f / MAXV[c]) : 0.f;
        SELFT[j] = f2bf(v);
    } else if (idx < 278528) {               // HEADW [32][512]: rows 0-8 a0, 9-18 a1, 19 value
        int j = idx - 262144;
        int n = j >> 9, k = j & 511;
        float v = 0.f;
        if (n < 9) v = a0w[n * 512 + k];
        else if (n < 19) v = a1w[(n - 9) * 512 + k];
        else if (n == 19) v = vw[k];
        HEADW[j] = f2bf(v);
    } else if (idx < 279328) {               // BIAS[800]
        int j = idx - 278528;
        float v = 0.f;
        if (j < 128) v = c1b[j];
        else if (j < 256) v = c2b[j - 128];
        else if (j < 512) v = fcb[j - 256];
        else if (j < 768) v = sfb[j - 512];
        else {
            int j2 = j - 768;
            if (j2 < 9) v = a0b[j2]; else if (j2 < 19) v = a1b[j2 - 9]; else if (j2 == 19) v = vb[0];
        }
        BIAS[j] = v;
    }
}

// ---------------- K12: scatter+dedupe (token-recheck) -> im2col LDS -> conv1 GEMM ----------------
union RegionU {
    int box[4 * 2662];        // 42,592 B (scatter phase: 4 samples)
    u16 bt[2][128 * 72];      // 36,864 B (GEMM phase: double-buffered B tile)
};

__global__ __launch_bounds__(256) void k12_kernel(
    const int* __restrict__ obs, const u16* __restrict__ W1T,
    const float* __restrict__ BIAS, u16* __restrict__ h1, u16* __restrict__ s22g)
{
    __shared__ __align__(16) u16 A[80 * 584];     // 93,440 B
    __shared__ __align__(16) RegionU R;
    __shared__ u16 s22[256];
    const int tid = threadIdx.x, w = tid >> 6, l = tid & 63;
    const int s0 = blockIdx.x * 8;

    {
        short8 z = {0, 0, 0, 0, 0, 0, 0, 0};
        for (int i = tid; i < 5840; i += 256) *(short8*)(A + i * 8) = z;
        s22[tid] = 0;
    }
    const int sub = tid / 50;                 // sample-in-phase (valid for tid<200)
    const int mbase = tid * 4 - sub * 200;    // token index within sample

    for (int ph = 0; ph < 2; ++ph) {
        __syncthreads();                      // box region free (prev recheck / A-zero done)
        {
            int4 zz = {0, 0, 0, 0};
            for (int i = tid; i < 2662; i += 256) ((int4*)R.box)[i] = zz;
        }
        int4 t0, t1, t2;
        if (tid < 200) {                      // issue loads before barrier (overlap)
            const int4* tp = (const int4*)(obs + ((long)(s0 + ph * 4) * 200 + tid * 4) * 3);
            t0 = tp[0]; t1 = tp[1]; t2 = tp[2];
        }
        __syncthreads();                      // box cleared
        int cell[4], enc[4], vv[4], xv[4], yv[4], av[4], ok[4];
        if (tid < 200) {
            int raw[12] = {t0.x, t0.y, t0.z, t0.w, t1.x, t1.y, t1.z, t1.w, t2.x, t2.y, t2.z, t2.w};
            #pragma unroll
            for (int j = 0; j < 4; ++j) {
                int c = raw[j * 3], a = raw[j * 3 + 1], v = raw[j * 3 + 2];
                c = (c == 255) ? 0 : c; a = (a == 255) ? 0 : a; v = (v == 255) ? 0 : v;
                int xs = (c >> 4) & 15, ys = c & 15;
                ok[j] = ((unsigned)a < 22u) & (xs < 11) & (ys < 11);
                cell[j] = sub * 2662 + a * 121 + xs * 11 + ys;
                enc[j] = ((mbase + j) << 8) | (v & 255);
                vv[j] = v; xv[j] = xs; yv[j] = ys; av[j] = a;
                if (ok[j]) atomicMax(&R.box[cell[j]], enc[j]);
            }
        }
        __syncthreads();                      // all atomics done
        if (tid < 200) {
            #pragma unroll
            for (int j = 0; j < 4; ++j) {
                if (ok[j] && R.box[cell[j]] == enc[j]) {   // this token won the cell
                    u16 bv = f2bf((float)vv[j]);
                    int ls = ph * 4 + sub;
                    if (xv[j] == 5 && yv[j] == 5) s22[ls * 32 + av[j]] = bv;
                    int bcol = av[j] * 25;
                    #pragma unroll
                    for (int ox = 0; ox < 3; ++ox) {
                        int kx = xv[j] - 3 * ox;
                        if ((unsigned)kx > 4u) continue;
                        #pragma unroll
                        for (int oy = 0; oy < 3; ++oy) {
                            int ky = yv[j] - 3 * oy;
                            if ((unsigned)ky > 4u) continue;
                            A[(ls * 9 + ox * 3 + oy) * 584 + bcol + kx * 5 + ky] = bv;
                        }
                    }
                }
            }
        }
    }
    __syncthreads();                          // A + s22 complete; box region free for bt
    s22g[s0 * 32 + tid] = s22[tid];

    // GEMM [80 x 576] x [576 x 128], B double-buffered with reg-staged prefetch.
    f32x4 acc[5][2];
    const f32x4 fz = {0.f, 0.f, 0.f, 0.f};
    #pragma unroll
    for (int i = 0; i < 5; ++i) { acc[i][0] = fz; acc[i][1] = fz; }

    short8 breg[4];
    #pragma unroll
    for (int q = 0; q < 4; ++q) {
        int s = tid + q * 256;
        breg[q] = *(const short8*)(W1T + (s >> 3) * 576 + (s & 7) * 8);
    }
    #pragma unroll
    for (int q = 0; q < 4; ++q) {
        int s = tid + q * 256;
        *(short8*)(R.bt[0] + (s >> 3) * 72 + (s & 7) * 8) = breg[q];
    }
    __syncthreads();

    for (int kc = 0; kc < 9; ++kc) {
        if (kc < 8) {
            #pragma unroll
            for (int q = 0; q < 4; ++q) {
                int s = tid + q * 256;
                breg[q] = *(const short8*)(W1T + (s >> 3) * 576 + (kc + 1) * 64 + (s & 7) * 8);
            }
        }
        const u16* bt = R.bt[kc & 1];
        const int colw = w * 32;
        #pragma unroll
        for (int ks = 0; ks < 2; ++ks) {
            short8 b0 = *(const short8*)(bt + (colw + (l & 15)) * 72 + ks * 32 + ((l >> 4) << 3));
            short8 b1 = *(const short8*)(bt + (colw + 16 + (l & 15)) * 72 + ks * 32 + ((l >> 4) << 3));
            #pragma unroll
            for (int mt = 0; mt < 5; ++mt) {
                short8 a = *(const short8*)(A + (mt * 16 + (l & 15)) * 584 + kc * 64 + ks * 32 + ((l >> 4) << 3));
                acc[mt][0] = MFMA16(a, b0, acc[mt][0]);
                acc[mt][1] = MFMA16(a, b1, acc[mt][1]);
            }
        }
        if (kc < 8) {
            u16* bd = R.bt[(kc + 1) & 1];
            #pragma unroll
            for (int q = 0; q < 4; ++q) {
                int s = tid + q * 256;
                *(short8*)(bd + (s >> 3) * 72 + (s & 7) * 8) = breg[q];
            }
        }
        __syncthreads();
    }

    const long h1base = (long)blockIdx.x * 72 * 128;
    #pragma unroll
    for (int mt = 0; mt < 5; ++mt) {
        #pragma unroll
        for (int nt = 0; nt < 2; ++nt) {
            int col = w * 32 + nt * 16 + (l & 15);
            float bias = BIAS[col];
            #pragma unroll
            for (int r = 0; r < 4; ++r) {
                int row = mt * 16 + ((l >> 4) << 2) + r;
                if (row < 72) {
                    float v = acc[mt][nt][r] + bias;
                    v = v > 0.f ? v : 0.f;
                    h1[h1base + (long)row * 128 + col] = f2bf(v);
                }
            }
        }
    }
}

// ---------------- K3: conv2 (dbuf) + fc + self + heads, 64 samples/WG ----------------
union BbU {
    u16 c2[2][128 * 72];      // conv2 double-buffered B
    u16 big[256 * 72];        // fc / self / heads B
};

__global__ __launch_bounds__(256) void k3_kernel(
    const u16* __restrict__ h1, const u16* __restrict__ s22g,
    const u16* __restrict__ W2T, const u16* __restrict__ FCT,
    const u16* __restrict__ SELFT, const u16* __restrict__ HEADW,
    const float* __restrict__ BIAS, float* __restrict__ out, int B)
{
    __shared__ __align__(16) u16 A3[64 * 136];    // 17,408
    __shared__ __align__(16) u16 HID[64 * 520];   // 66,560
    __shared__ __align__(16) u16 Ab[2][64 * 72];  // 18,432
    __shared__ __align__(16) BbU Bb;              // 36,864
    const int tid = threadIdx.x, w = tid >> 6, l = tid & 63;
    const int s0 = blockIdx.x * 64;
    const float* c2b = BIAS + 128;
    const float* fcb = BIAS + 256;
    const float* sfb = BIAS + 512;
    const float* hdb = BIAS + 768;
    const f32x4 fz = {0.f, 0.f, 0.f, 0.f};

    f32x4 acc[4][4];

    // ---- conv2: [64,1152] @ W2T[128][1152], A+B double-buffered ----
    #pragma unroll
    for (int i = 0; i < 4; ++i) { acc[i][0] = fz; acc[i][1] = fz; }

    short8 areg[2], bregc[4];
    #pragma unroll
    for (int q = 0; q < 2; ++q) {
        int s = tid + q * 256;
        areg[q] = *(const short8*)(h1 + (long)(s0 + (s >> 3)) * 1152 + (s & 7) * 8);
    }
    #pragma unroll
    for (int q = 0; q < 4; ++q) {
        int s = tid + q * 256;
        bregc[q] = *(const short8*)(W2T + (s >> 3) * 1152 + (s & 7) * 8);
    }
    #pragma unroll
    for (int q = 0; q < 2; ++q) {
        int s = tid + q * 256;
        *(short8*)(Ab[0] + (s >> 3) * 72 + (s & 7) * 8) = areg[q];
    }
    #pragma unroll
    for (int q = 0; q < 4; ++q) {
        int s = tid + q * 256;
        *(short8*)(Bb.c2[0] + (s >> 3) * 72 + (s & 7) * 8) = bregc[q];
    }
    __syncthreads();

    for (int kc = 0; kc < 18; ++kc) {
        if (kc < 17) {
            #pragma unroll
            for (int q = 0; q < 2; ++q) {
                int s = tid + q * 256;
                areg[q] = *(const short8*)(h1 + (long)(s0 + (s >> 3)) * 1152 + (kc + 1) * 64 + (s & 7) * 8);
            }
            #pragma unroll
            for (int q = 0; q < 4; ++q) {
                int s = tid + q * 256;
                bregc[q] = *(const short8*)(W2T + (s >> 3) * 1152 + (kc + 1) * 64 + (s & 7) * 8);
            }
        }
        const u16* ab = Ab[kc & 1];
        const u16* bb = Bb.c2[kc & 1];
        const int colw = w * 32;
        #pragma unroll
        for (int ks = 0; ks < 2; ++ks) {
            short8 b0 = *(const short8*)(bb + (colw + (l & 15)) * 72 + ks * 32 + ((l >> 4) << 3));
            short8 b1 = *(const short8*)(bb + (colw + 16 + (l & 15)) * 72 + ks * 32 + ((l >> 4) << 3));
            #pragma unroll
            for (int mt = 0; mt < 4; ++mt) {
                short8 a = *(const short8*)(ab + (mt * 16 + (l & 15)) * 72 + ks * 32 + ((l >> 4) << 3));
                acc[mt][0] = MFMA16(a, b0, acc[mt][0]);
                acc[mt][1] = MFMA16(a, b1, acc[mt][1]);
            }
        }
        if (kc < 17) {
            u16* ad = Ab[(kc + 1) & 1];
            u16* bd = Bb.c2[(kc + 1) & 1];
            #pragma unroll
            for (int q = 0; q < 2; ++q) {
                int s = tid + q * 256;
                *(short8*)(ad + (s >> 3) * 72 + (s & 7) * 8) = areg[q];
            }
            #pragma unroll
            for (int q = 0; q < 4; ++q) {
                int s = tid + q * 256;
                *(short8*)(bd + (s >> 3) * 72 + (s & 7) * 8) = bregc[q];
            }
        }
        __syncthreads();
    }
    {
        const int colw = w * 32;
        #pragma unroll
        for (int mt = 0; mt < 4; ++mt)
            #pragma unroll
            for (int nt = 0; nt < 2; ++nt) {
                int col = colw + nt * 16 + (l & 15);
                float bias = c2b[col];
                #pragma unroll
                for (int r = 0; r < 4; ++r) {
                    int row = mt * 16 + ((l >> 4) << 2) + r;
                    float v = acc[mt][nt][r] + bias; v = v > 0.f ? v : 0.f;
                    A3[row * 136 + col] = f2bf(v);
                }
            }
    }

    // ---- fc: A3[64][128] @ FCT[256][128] -> HID cols 256..511 ----
    #pragma unroll
    for (int i = 0; i < 4; ++i) for (int j = 0; j < 4; ++j) acc[i][j] = fz;
    for (int kc = 0; kc < 2; ++kc) {
        __syncthreads();
        for (int s = tid; s < 2048; s += 256) {
            int n = s >> 3, seg = s & 7;
            *(short8*)(Bb.big + n * 72 + seg * 8) = *(const short8*)(FCT + n * 128 + kc * 64 + seg * 8);
        }
        __syncthreads();
        const int colw = w * 64;
        #pragma unroll
        for (int ks = 0; ks < 2; ++ks) {
            short8 b[4];
            #pragma unroll
            for (int nt = 0; nt < 4; ++nt)
                b[nt] = *(const short8*)(Bb.big + (colw + nt * 16 + (l & 15)) * 72 + ks * 32 + ((l >> 4) << 3));
            #pragma unroll
            for (int mt = 0; mt < 4; ++mt) {
                short8 a = *(const short8*)(A3 + (mt * 16 + (l & 15)) * 136 + kc * 64 + ks * 32 + ((l >> 4) << 3));
                #pragma unroll
                for (int nt = 0; nt < 4; ++nt) acc[mt][nt] = MFMA16(a, b[nt], acc[mt][nt]);
            }
        }
    }
    {
        const int colw = w * 64;
        #pragma unroll
        for (int mt = 0; mt < 4; ++mt)
            #pragma unroll
            for (int nt = 0; nt < 4; ++nt) {
                int col = colw + nt * 16 + (l & 15);
                float bias = fcb[col];
                #pragma unroll
                for (int r = 0; r < 4; ++r) {
                    int row = mt * 16 + ((l >> 4) << 2) + r;
                    float v = acc[mt][nt][r] + bias; v = v > 0.f ? v : 0.f;
                    HID[row * 520 + 256 + col] = f2bf(v);
                }
            }
    }
    __syncthreads();

    // ---- self: s22[64][32] @ SELFT[256][32] -> HID cols 0..255 ----
    #pragma unroll
    for (int i = 0; i < 4; ++i) for (int j = 0; j < 4; ++j) acc[i][j] = fz;
    for (int s = tid; s < 256; s += 256) {
        int r = s >> 2, seg = s & 3;
        *(short8*)(Ab[0] + r * 72 + seg * 8) = *(const short8*)(s22g + (s0 + r) * 32 + seg * 8);
    }
    for (int s = tid; s < 1024; s += 256) {
        int n = s >> 2, seg = s & 3;
        *(short8*)(Bb.big + n * 72 + seg * 8) = *(const short8*)(SELFT + n * 32 + seg * 8);
    }
    __syncthreads();
    {
        const int colw = w * 64;
        short8 b[4];
        #pragma unroll
        for (int nt = 0; nt < 4; ++nt)
            b[nt] = *(const short8*)(Bb.big + (colw + nt * 16 + (l & 15)) * 72 + ((l >> 4) << 3));
        #pragma unroll
        for (int mt = 0; mt < 4; ++mt) {
            short8 a = *(const short8*)(Ab[0] + (mt * 16 + (l & 15)) * 72 + ((l >> 4) << 3));
            #pragma unroll
            for (int nt = 0; nt < 4; ++nt) acc[mt][nt] = MFMA16(a, b[nt], acc[mt][nt]);
        }
        #pragma unroll
        for (int mt = 0; mt < 4; ++mt)
            #pragma unroll
            for (int nt = 0; nt < 4; ++nt) {
                int col = colw + nt * 16 + (l & 15);
                float bias = sfb[col];
                #pragma unroll
                for (int r = 0; r < 4; ++r) {
                    int row = mt * 16 + ((l >> 4) << 2) + r;
                    float v = acc[mt][nt][r] + bias; v = v > 0.f ? v : 0.f;
                    HID[row * 520 + col] = f2bf(v);
                }
            }
    }

    // ---- heads: HID[64][512] @ HEADW[32][512]; wave w owns rows w*16..w*16+15 ----
    f32x4 hacc[2]; hacc[0] = fz; hacc[1] = fz;
    for (int kc = 0; kc < 8; ++kc) {
        __syncthreads();
        for (int s = tid; s < 256; s += 256) {
            int r = s >> 3, seg = s & 7;
            *(short8*)(Bb.big + r * 72 + seg * 8) = *(const short8*)(HEADW + r * 512 + kc * 64 + seg * 8);
        }
        __syncthreads();
        #pragma unroll
        for (int ks = 0; ks < 2; ++ks) {
            short8 a  = *(const short8*)(HID + (w * 16 + (l & 15)) * 520 + kc * 64 + ks * 32 + ((l >> 4) << 3));
            short8 b0 = *(const short8*)(Bb.big + ((l & 15)) * 72 + ks * 32 + ((l >> 4) << 3));
            short8 b1 = *(const short8*)(Bb.big + (16 + (l & 15)) * 72 + ks * 32 + ((l >> 4) << 3));
            hacc[0] = MFMA16(a, b0, hacc[0]);
            hacc[1] = MFMA16(a, b1, hacc[1]);
        }
    }
    #pragma unroll
    for (int nt = 0; nt < 2; ++nt) {
        #pragma unroll
        for (int r = 0; r < 4; ++r) {
            int srow = s0 + w * 16 + ((l >> 4) << 2) + r;
            int col = nt * 16 + (l & 15);
            float v = hacc[nt][r] + hdb[col];
            if (col < 9) out[(long)srow * 9 + col] = v;
            else if (col < 19) out[(long)B * 9 + (long)srow * 10 + (col - 9)] = v;
            else if (col == 19) out[(long)B * 19 + srow] = v;
        }
    }
}

extern "C" void kernel_launch(void* const* d_in, const int* in_sizes, int n_in,
                              void* d_out, int out_size, void* d_ws, size_t ws_size,
                              hipStream_t stream)
{
    const int*   obs = (const int*)d_in[0];
    const float* c1w = (const float*)d_in[1];
    const float* c1b = (const float*)d_in[2];
    const float* c2w = (const float*)d_in[3];
    const float* c2b = (const float*)d_in[4];
    const float* fcw = (const float*)d_in[5];
    const float* fcb = (const float*)d_in[6];
    const float* sfw = (const float*)d_in[7];
    const float* sfb = (const float*)d_in[8];
    const float* a0w = (const float*)d_in[9];
    const float* a0b = (const float*)d_in[10];
    const float* a1w = (const float*)d_in[11];
    const float* a1b = (const float*)d_in[12];
    const float* vw  = (const float*)d_in[13];
    const float* vb  = (const float*)d_in[14];
    const int B = in_sizes[0] / 600;   // 16384

    char* ws = (char*)d_ws;
    u16*   W1T   = (u16*)(ws + 0);
    u16*   W2T   = (u16*)(ws + 147456);
    u16*   FCT   = (u16*)(ws + 442368);
    u16*   SELFT = (u16*)(ws + 507904);
    u16*   HEADW = (u16*)(ws + 524288);
    float* BIAS  = (float*)(ws + 557056);
    u16*   s22g  = (u16*)(ws + 560256);
    u16*   h1    = (u16*)(ws + 560256 + (size_t)B * 64);

    prep_kernel<<<1092, 256, 0, stream>>>(c1w, c1b, c2w, c2b, fcw, fcb, sfw, sfb,
                                          a0w, a0b, a1w, a1b, vw, vb,
                                          W1T, W2T, FCT, SELFT, HEADW, BIAS);
    k12_kernel<<<B / 8, 256, 0, stream>>>(obs, W1T, BIAS, h1, s22g);
    k3_kernel<<<B / 64, 256, 0, stream>>>(h1, s22g, W2T, FCT, SELFT, HEADW, BIAS,
                                          (float*)d_out, B);
}

// Round 4
// 124.198 us; speedup vs baseline: 3.7467x; 1.0961x over previous
//
#include <hip/hip_runtime.h>

typedef unsigned short u16;
typedef __attribute__((ext_vector_type(8))) short short8;
typedef __attribute__((ext_vector_type(4))) float f32x4;

#define MFMA16(a, b, c) __builtin_amdgcn_mfma_f32_16x16x32_bf16((a), (b), (c), 0, 0, 0)

__device__ __forceinline__ u16 f2bf(float f) {
    unsigned u = __float_as_uint(f);
    unsigned r = (u + 0x7FFFu + ((u >> 16) & 1u)) >> 16;
    return (u16)r;
}

__device__ const float MAXV[22] = {9.f, 1.f, 1.f, 10.f, 3.f, 254.f, 1.f, 1.f, 235.f, 8.f, 9.f,
                                   250.f, 29.f, 1.f, 1.f, 8.f, 1.f, 1.f, 6.f, 3.f, 1.f, 2.f};

// ---------------- prep: weights -> bf16, 1/MAX folded ----------------
// W1F: frag-ordered conv1 weights. grp = (g*18 + ks), g = n>>4 (0..7), ks = k-slot (0..17).
// W1F[grp*512 + l*8 + e] = w1[n = g*16 + (l&15)][k = ks*32 + (l>>4)*8 + e]  (k<550, else 0)
__global__ void prep_kernel(
    const float* c1w, const float* c1b, const float* c2w, const float* c2b,
    const float* fcw, const float* fcb, const float* sfw, const float* sfb,
    const float* a0w, const float* a0b, const float* a1w, const float* a1b,
    const float* vw, const float* vb,
    u16* W1F, u16* W2T, u16* FCT, u16* SELFT, u16* HEADW, float* BIAS)
{
    int idx = blockIdx.x * 256 + threadIdx.x;
    if (idx < 73728) {                       // W1F frag layout
        int grp = idx >> 9, off = idx & 511;
        int g = grp / 18, ks = grp - g * 18;
        int l = off >> 3, e = off & 7;
        int n = g * 16 + (l & 15);
        int k = ks * 32 + ((l >> 4) << 3) + e;
        float v = 0.f;
        if (k < 550) { int c = k / 25; v = c1w[n * 550 + k] * (1.0f / MAXV[c]); }
        W1F[idx] = f2bf(v);
    } else if (idx < 221184) {               // W2T [128][1152]: k = p*128 + ic
        int j = idx - 73728;
        int oc = j / 1152, k = j - oc * 1152;
        int p = k >> 7, ic = k & 127;
        W2T[j] = f2bf(c2w[oc * 1152 + ic * 9 + p]);
    } else if (idx < 253952) {               // FCT [256][128]
        int j = idx - 221184;
        FCT[j] = f2bf(fcw[j]);
    } else if (idx < 262144) {               // SELFT [256][32]
        int j = idx - 253952;
        int n = j >> 5, c = j & 31;
        float v = (c < 22) ? sfw[n * 22 + c] * (1.0f / MAXV[c]) : 0.f;
        SELFT[j] = f2bf(v);
    } else if (idx < 278528) {               // HEADW [32][512]
        int j = idx - 262144;
        int n = j >> 9, k = j & 511;
        float v = 0.f;
        if (n < 9) v = a0w[n * 512 + k];
        else if (n < 19) v = a1w[(n - 9) * 512 + k];
        else if (n == 19) v = vw[k];
        HEADW[j] = f2bf(v);
    } else if (idx < 279328) {               // BIAS[800]
        int j = idx - 278528;
        float v = 0.f;
        if (j < 128) v = c1b[j];
        else if (j < 256) v = c2b[j - 128];
        else if (j < 512) v = fcb[j - 256];
        else if (j < 768) v = sfb[j - 512];
        else {
            int j2 = j - 768;
            if (j2 < 9) v = a0b[j2]; else if (j2 < 19) v = a1b[j2 - 9]; else if (j2 == 19) v = vb[0];
        }
        BIAS[j] = v;
    }
}

// ---------------- K12: scatter -> im2col LDS (XOR-swizzled) -> barrier-free GEMM ----------------
// 8 samples/WG, 1 WG/CU. A [72][576] bf16, swizzle: byte ^= (row&7)<<4 (16B-slot XOR).
// B (conv1 weights) entirely in registers: bfr[2][18] short8 per wave (144 VGPR).
__global__ __launch_bounds__(256, 1) void k12_kernel(
    const int* __restrict__ obs, const u16* __restrict__ W1F,
    const float* __restrict__ BIAS, u16* __restrict__ h1, u16* __restrict__ s22g)
{
    __shared__ __align__(16) u16 A[72 * 576];     // 82,944 B
    __shared__ __align__(16) int box[4 * 2662];   // 42,592 B
    __shared__ u16 s22[256];                      //    512 B
    const int tid = threadIdx.x, w = tid >> 6, l = tid & 63;
    const int s0 = blockIdx.x * 8;

    // prefetch obs tokens for both phases (tid<200: sample sub=tid/50, tokens (tid%50)*4..+3)
    int4 t0[3], t1[3];
    const int sub = tid / 50;
    const int tq = tid - sub * 50;
    if (tid < 200) {
        const int4* p0 = (const int4*)(obs + ((long)(s0 + sub) * 200 + tq * 4) * 3);
        const int4* p1 = (const int4*)(obs + ((long)(s0 + 4 + sub) * 200 + tq * 4) * 3);
        t0[0] = p0[0]; t0[1] = p0[1]; t0[2] = p0[2];
        t1[0] = p1[0]; t1[1] = p1[1]; t1[2] = p1[2];
    }

    // B fragments: fully-coalesced loads, in flight during scatter
    short8 bfr[2][18];
    #pragma unroll
    for (int nt = 0; nt < 2; ++nt)
        #pragma unroll
        for (int ks = 0; ks < 18; ++ks)
            bfr[nt][ks] = *(const short8*)(W1F + (((w * 2 + nt) * 18 + ks) << 9) + l * 8);

    // zero A + box + s22
    {
        short8 z = {0, 0, 0, 0, 0, 0, 0, 0};
        for (int i = tid; i < 5184; i += 256) *(short8*)(A + i * 8) = z;
        int4 zz = {0, 0, 0, 0};
        for (int i = tid; i < 2662; i += 256) ((int4*)box)[i] = zz;
        s22[tid] = 0;
    }
    __syncthreads();

    // ---- scatter phase 0 (samples s0..s0+3) ----
    int ce[4], en[4], va[4], xa[4], ya[4], aa[4], ok[4];
    if (tid < 200) {
        int raw[12] = {t0[0].x, t0[0].y, t0[0].z, t0[0].w, t0[1].x, t0[1].y,
                       t0[1].z, t0[1].w, t0[2].x, t0[2].y, t0[2].z, t0[2].w};
        #pragma unroll
        for (int j = 0; j < 4; ++j) {
            int c = raw[j * 3], a = raw[j * 3 + 1], v = raw[j * 3 + 2];
            c = (c == 255) ? 0 : c; a = (a == 255) ? 0 : a; v = (v == 255) ? 0 : v;
            int xs = (c >> 4) & 15, ys = c & 15;
            ok[j] = ((unsigned)a < 22u) & (xs < 11) & (ys < 11);
            ce[j] = sub * 2662 + a * 121 + xs * 11 + ys;
            en[j] = ((tq * 4 + j) << 8) | (v & 255);
            va[j] = v; xa[j] = xs; ya[j] = ys; aa[j] = a;
            if (ok[j]) atomicMax(&box[ce[j]], en[j]);
        }
    }
    __syncthreads();
    if (tid < 200) {
        #pragma unroll
        for (int j = 0; j < 4; ++j) {
            if (ok[j] && box[ce[j]] == en[j]) {
                u16 bv = f2bf((float)va[j]);
                int ls = sub;
                if (xa[j] == 5 && ya[j] == 5) s22[ls * 32 + aa[j]] = bv;
                int bcol = aa[j] * 25;
                #pragma unroll
                for (int ox = 0; ox < 3; ++ox) {
                    int kx = xa[j] - 3 * ox;
                    if ((unsigned)kx > 4u) continue;
                    #pragma unroll
                    for (int oy = 0; oy < 3; ++oy) {
                        int ky = ya[j] - 3 * oy;
                        if ((unsigned)ky > 4u) continue;
                        int row = ls * 9 + ox * 3 + oy;
                        int byte = ((row * 576 + bcol + kx * 5 + ky) << 1) ^ ((row & 7) << 4);
                        *(u16*)((char*)A + byte) = bv;
                    }
                }
            }
        }
    }
    __syncthreads();
    if (tid < 200) {                           // token-targeted box re-clear
        #pragma unroll
        for (int j = 0; j < 4; ++j) if (ok[j]) box[ce[j]] = 0;
    }
    __syncthreads();

    // ---- scatter phase 1 (samples s0+4..s0+7) ----
    if (tid < 200) {
        int raw[12] = {t1[0].x, t1[0].y, t1[0].z, t1[0].w, t1[1].x, t1[1].y,
                       t1[1].z, t1[1].w, t1[2].x, t1[2].y, t1[2].z, t1[2].w};
        #pragma unroll
        for (int j = 0; j < 4; ++j) {
            int c = raw[j * 3], a = raw[j * 3 + 1], v = raw[j * 3 + 2];
            c = (c == 255) ? 0 : c; a = (a == 255) ? 0 : a; v = (v == 255) ? 0 : v;
            int xs = (c >> 4) & 15, ys = c & 15;
            ok[j] = ((unsigned)a < 22u) & (xs < 11) & (ys < 11);
            ce[j] = sub * 2662 + a * 121 + xs * 11 + ys;
            en[j] = ((tq * 4 + j) << 8) | (v & 255);
            va[j] = v; xa[j] = xs; ya[j] = ys; aa[j] = a;
            if (ok[j]) atomicMax(&box[ce[j]], en[j]);
        }
    }
    __syncthreads();
    if (tid < 200) {
        #pragma unroll
        for (int j = 0; j < 4; ++j) {
            if (ok[j] && box[ce[j]] == en[j]) {
                u16 bv = f2bf((float)va[j]);
                int ls = 4 + sub;
                if (xa[j] == 5 && ya[j] == 5) s22[ls * 32 + aa[j]] = bv;
                int bcol = aa[j] * 25;
                #pragma unroll
                for (int ox = 0; ox < 3; ++ox) {
                    int kx = xa[j] - 3 * ox;
                    if ((unsigned)kx > 4u) continue;
                    #pragma unroll
                    for (int oy = 0; oy < 3; ++oy) {
                        int ky = ya[j] - 3 * oy;
                        if ((unsigned)ky > 4u) continue;
                        int row = ls * 9 + ox * 3 + oy;
                        int byte = ((row * 576 + bcol + kx * 5 + ky) << 1) ^ ((row & 7) << 4);
                        *(u16*)((char*)A + byte) = bv;
                    }
                }
            }
        }
    }
    __syncthreads();                           // A + s22 final
    s22g[s0 * 32 + tid] = s22[tid];

    // ---- barrier-free GEMM: [80(72) x 576] x regs[576 x 32] per wave ----
    f32x4 acc[5][2];
    const f32x4 fz = {0.f, 0.f, 0.f, 0.f};
    #pragma unroll
    for (int i = 0; i < 5; ++i) { acc[i][0] = fz; acc[i][1] = fz; }

    #pragma unroll
    for (int ks = 0; ks < 18; ++ks) {
        short8 a[5];
        #pragma unroll
        for (int mt = 0; mt < 5; ++mt) {
            int row = mt * 16 + (l & 15);
            row = row < 72 ? row : 71;                       // clamp (dup rows discarded at store)
            int off = ((row * 576 + ks * 32 + ((l >> 4) << 3)) << 1) ^ ((row & 7) << 4);
            a[mt] = *(const short8*)((const char*)A + off);
        }
        #pragma unroll
        for (int mt = 0; mt < 5; ++mt) {
            acc[mt][0] = MFMA16(a[mt], bfr[0][ks], acc[mt][0]);
            acc[mt][1] = MFMA16(a[mt], bfr[1][ks], acc[mt][1]);
        }
    }

    #pragma unroll
    for (int mt = 0; mt < 5; ++mt) {
        #pragma unroll
        for (int nt = 0; nt < 2; ++nt) {
            int col = w * 32 + nt * 16 + (l & 15);
            float bias = BIAS[col];
            #pragma unroll
            for (int r = 0; r < 4; ++r) {
                int row = mt * 16 + ((l >> 4) << 2) + r;
                if (row < 72) {
                    int s = row / 9;
                    int pos = row - s * 9;
                    float v = acc[mt][nt][r] + bias;
                    v = v > 0.f ? v : 0.f;
                    h1[((long)(s0 + s)) * 1152 + pos * 128 + col] = f2bf(v);
                }
            }
        }
    }
}

// ---------------- K3: conv2 (dbuf) + fc + self + heads, 64 samples/WG ----------------
union BbU {
    u16 c2[2][128 * 72];
    u16 big[256 * 72];
};

__global__ __launch_bounds__(256) void k3_kernel(
    const u16* __restrict__ h1, const u16* __restrict__ s22g,
    const u16* __restrict__ W2T, const u16* __restrict__ FCT,
    const u16* __restrict__ SELFT, const u16* __restrict__ HEADW,
    const float* __restrict__ BIAS, float* __restrict__ out, int B)
{
    __shared__ __align__(16) u16 A3[64 * 136];
    __shared__ __align__(16) u16 HID[64 * 520];
    __shared__ __align__(16) u16 Ab[2][64 * 72];
    __shared__ __align__(16) BbU Bb;
    const int tid = threadIdx.x, w = tid >> 6, l = tid & 63;
    const int s0 = blockIdx.x * 64;
    const float* c2b = BIAS + 128;
    const float* fcb = BIAS + 256;
    const float* sfb = BIAS + 512;
    const float* hdb = BIAS + 768;
    const f32x4 fz = {0.f, 0.f, 0.f, 0.f};

    f32x4 acc[4][4];

    // ---- conv2: [64,1152] @ W2T[128][1152], A+B double-buffered ----
    #pragma unroll
    for (int i = 0; i < 4; ++i) { acc[i][0] = fz; acc[i][1] = fz; }

    short8 areg[2], bregc[4];
    #pragma unroll
    for (int q = 0; q < 2; ++q) {
        int s = tid + q * 256;
        areg[q] = *(const short8*)(h1 + (long)(s0 + (s >> 3)) * 1152 + (s & 7) * 8);
    }
    #pragma unroll
    for (int q = 0; q < 4; ++q) {
        int s = tid + q * 256;
        bregc[q] = *(const short8*)(W2T + (s >> 3) * 1152 + (s & 7) * 8);
    }
    #pragma unroll
    for (int q = 0; q < 2; ++q) {
        int s = tid + q * 256;
        *(short8*)(Ab[0] + (s >> 3) * 72 + (s & 7) * 8) = areg[q];
    }
    #pragma unroll
    for (int q = 0; q < 4; ++q) {
        int s = tid + q * 256;
        *(short8*)(Bb.c2[0] + (s >> 3) * 72 + (s & 7) * 8) = bregc[q];
    }
    __syncthreads();

    for (int kc = 0; kc < 18; ++kc) {
        if (kc < 17) {
            #pragma unroll
            for (int q = 0; q < 2; ++q) {
                int s = tid + q * 256;
                areg[q] = *(const short8*)(h1 + (long)(s0 + (s >> 3)) * 1152 + (kc + 1) * 64 + (s & 7) * 8);
            }
            #pragma unroll
            for (int q = 0; q < 4; ++q) {
                int s = tid + q * 256;
                bregc[q] = *(const short8*)(W2T + (s >> 3) * 1152 + (kc + 1) * 64 + (s & 7) * 8);
            }
        }
        const u16* ab = Ab[kc & 1];
        const u16* bb = Bb.c2[kc & 1];
        const int colw = w * 32;
        #pragma unroll
        for (int ks = 0; ks < 2; ++ks) {
            short8 b0 = *(const short8*)(bb + (colw + (l & 15)) * 72 + ks * 32 + ((l >> 4) << 3));
            short8 b1 = *(const short8*)(bb + (colw + 16 + (l & 15)) * 72 + ks * 32 + ((l >> 4) << 3));
            #pragma unroll
            for (int mt = 0; mt < 4; ++mt) {
                short8 a = *(const short8*)(ab + (mt * 16 + (l & 15)) * 72 + ks * 32 + ((l >> 4) << 3));
                acc[mt][0] = MFMA16(a, b0, acc[mt][0]);
                acc[mt][1] = MFMA16(a, b1, acc[mt][1]);
            }
        }
        if (kc < 17) {
            u16* ad = Ab[(kc + 1) & 1];
            u16* bd = Bb.c2[(kc + 1) & 1];
            #pragma unroll
            for (int q = 0; q < 2; ++q) {
                int s = tid + q * 256;
                *(short8*)(ad + (s >> 3) * 72 + (s & 7) * 8) = areg[q];
            }
            #pragma unroll
            for (int q = 0; q < 4; ++q) {
                int s = tid + q * 256;
                *(short8*)(bd + (s >> 3) * 72 + (s & 7) * 8) = bregc[q];
            }
        }
        __syncthreads();
    }
    {
        const int colw = w * 32;
        #pragma unroll
        for (int mt = 0; mt < 4; ++mt)
            #pragma unroll
            for (int nt = 0; nt < 2; ++nt) {
                int col = colw + nt * 16 + (l & 15);
                float bias = c2b[col];
                #pragma unroll
                for (int r = 0; r < 4; ++r) {
                    int row = mt * 16 + ((l >> 4) << 2) + r;
                    float v = acc[mt][nt][r] + bias; v = v > 0.f ? v : 0.f;
                    A3[row * 136 + col] = f2bf(v);
                }
            }
    }

    // ---- fc: A3[64][128] @ FCT[256][128] -> HID cols 256..511 ----
    #pragma unroll
    for (int i = 0; i < 4; ++i) for (int j = 0; j < 4; ++j) acc[i][j] = fz;
    for (int kc = 0; kc < 2; ++kc) {
        __syncthreads();
        for (int s = tid; s < 2048; s += 256) {
            int n = s >> 3, seg = s & 7;
            *(short8*)(Bb.big + n * 72 + seg * 8) = *(const short8*)(FCT + n * 128 + kc * 64 + seg * 8);
        }
        __syncthreads();
        const int colw = w * 64;
        #pragma unroll
        for (int ks = 0; ks < 2; ++ks) {
            short8 b[4];
            #pragma unroll
            for (int nt = 0; nt < 4; ++nt)
                b[nt] = *(const short8*)(Bb.big + (colw + nt * 16 + (l & 15)) * 72 + ks * 32 + ((l >> 4) << 3));
            #pragma unroll
            for (int mt = 0; mt < 4; ++mt) {
                short8 a = *(const short8*)(A3 + (mt * 16 + (l & 15)) * 136 + kc * 64 + ks * 32 + ((l >> 4) << 3));
                #pragma unroll
                for (int nt = 0; nt < 4; ++nt) acc[mt][nt] = MFMA16(a, b[nt], acc[mt][nt]);
            }
        }
    }
    {
        const int colw = w * 64;
        #pragma unroll
        for (int mt = 0; mt < 4; ++mt)
            #pragma unroll
            for (int nt = 0; nt < 4; ++nt) {
                int col = colw + nt * 16 + (l & 15);
                float bias = fcb[col];
                #pragma unroll
                for (int r = 0; r < 4; ++r) {
                    int row = mt * 16 + ((l >> 4) << 2) + r;
                    float v = acc[mt][nt][r] + bias; v = v > 0.f ? v : 0.f;
                    HID[row * 520 + 256 + col] = f2bf(v);
                }
            }
    }
    __syncthreads();

    // ---- self: s22[64][32] @ SELFT[256][32] -> HID cols 0..255 ----
    #pragma unroll
    for (int i = 0; i < 4; ++i) for (int j = 0; j < 4; ++j) acc[i][j] = fz;
    for (int s = tid; s < 256; s += 256) {
        int r = s >> 2, seg = s & 3;
        *(short8*)(Ab[0] + r * 72 + seg * 8) = *(const short8*)(s22g + (s0 + r) * 32 + seg * 8);
    }
    for (int s = tid; s < 1024; s += 256) {
        int n = s >> 2, seg = s & 3;
        *(short8*)(Bb.big + n * 72 + seg * 8) = *(const short8*)(SELFT + n * 32 + seg * 8);
    }
    __syncthreads();
    {
        const int colw = w * 64;
        short8 b[4];
        #pragma unroll
        for (int nt = 0; nt < 4; ++nt)
            b[nt] = *(const short8*)(Bb.big + (colw + nt * 16 + (l & 15)) * 72 + ((l >> 4) << 3));
        #pragma unroll
        for (int mt = 0; mt < 4; ++mt) {
            short8 a = *(const short8*)(Ab[0] + (mt * 16 + (l & 15)) * 72 + ((l >> 4) << 3));
            #pragma unroll
            for (int nt = 0; nt < 4; ++nt) acc[mt][nt] = MFMA16(a, b[nt], acc[mt][nt]);
        }
        #pragma unroll
        for (int mt = 0; mt < 4; ++mt)
            #pragma unroll
            for (int nt = 0; nt < 4; ++nt) {
                int col = colw + nt * 16 + (l & 15);
                float bias = sfb[col];
                #pragma unroll
                for (int r = 0; r < 4; ++r) {
                    int row = mt * 16 + ((l >> 4) << 2) + r;
                    float v = acc[mt][nt][r] + bias; v = v > 0.f ? v : 0.f;
                    HID[row * 520 + col] = f2bf(v);
                }
            }
    }

    // ---- heads: HID[64][512] @ HEADW[32][512] ----
    f32x4 hacc[2]; hacc[0] = fz; hacc[1] = fz;
    for (int kc = 0; kc < 8; ++kc) {
        __syncthreads();
        for (int s = tid; s < 256; s += 256) {
            int r = s >> 3, seg = s & 7;
            *(short8*)(Bb.big + r * 72 + seg * 8) = *(const short8*)(HEADW + r * 512 + kc * 64 + seg * 8);
        }
        __syncthreads();
        #pragma unroll
        for (int ks = 0; ks < 2; ++ks) {
            short8 a  = *(const short8*)(HID + (w * 16 + (l & 15)) * 520 + kc * 64 + ks * 32 + ((l >> 4) << 3));
            short8 b0 = *(const short8*)(Bb.big + ((l & 15)) * 72 + ks * 32 + ((l >> 4) << 3));
            short8 b1 = *(const short8*)(Bb.big + (16 + (l & 15)) * 72 + ks * 32 + ((l >> 4) << 3));
            hacc[0] = MFMA16(a, b0, hacc[0]);
            hacc[1] = MFMA16(a, b1, hacc[1]);
        }
    }
    #pragma unroll
    for (int nt = 0; nt < 2; ++nt) {
        #pragma unroll
        for (int r = 0; r < 4; ++r) {
            int srow = s0 + w * 16 + ((l >> 4) << 2) + r;
            int col = nt * 16 + (l & 15);
            float v = hacc[nt][r] + hdb[col];
            if (col < 9) out[(long)srow * 9 + col] = v;
            else if (col < 19) out[(long)B * 9 + (long)srow * 10 + (col - 9)] = v;
            else if (col == 19) out[(long)B * 19 + srow] = v;
        }
    }
}

extern "C" void kernel_launch(void* const* d_in, const int* in_sizes, int n_in,
                              void* d_out, int out_size, void* d_ws, size_t ws_size,
                              hipStream_t stream)
{
    const int*   obs = (const int*)d_in[0];
    const float* c1w = (const float*)d_in[1];
    const float* c1b = (const float*)d_in[2];
    const float* c2w = (const float*)d_in[3];
    const float* c2b = (const float*)d_in[4];
    const float* fcw = (const float*)d_in[5];
    const float* fcb = (const float*)d_in[6];
    const float* sfw = (const float*)d_in[7];
    const float* sfb = (const float*)d_in[8];
    const float* a0w = (const float*)d_in[9];
    const float* a0b = (const float*)d_in[10];
    const float* a1w = (const float*)d_in[11];
    const float* a1b = (const float*)d_in[12];
    const float* vw  = (const float*)d_in[13];
    const float* vb  = (const float*)d_in[14];
    const int B = in_sizes[0] / 600;   // 16384

    char* ws = (char*)d_ws;
    u16*   W1F   = (u16*)(ws + 0);
    u16*   W2T   = (u16*)(ws + 147456);
    u16*   FCT   = (u16*)(ws + 442368);
    u16*   SELFT = (u16*)(ws + 507904);
    u16*   HEADW = (u16*)(ws + 524288);
    float* BIAS  = (float*)(ws + 557056);
    u16*   s22g  = (u16*)(ws + 560256);
    u16*   h1    = (u16*)(ws + 560256 + (size_t)B * 64);

    prep_kernel<<<1092, 256, 0, stream>>>(c1w, c1b, c2w, c2b, fcw, fcb, sfw, sfb,
                                          a0w, a0b, a1w, a1b, vw, vb,
                                          W1F, W2T, FCT, SELFT, HEADW, BIAS);
    k12_kernel<<<B / 8, 256, 0, stream>>>(obs, W1F, BIAS, h1, s22g);
    k3_kernel<<<B / 64, 256, 0, stream>>>(h1, s22g, W2T, FCT, SELFT, HEADW, BIAS,
                                          (float*)d_out, B);
}

// Round 5
// 98.130 us; speedup vs baseline: 4.7420x; 1.2656x over previous
//
#include <hip/hip_runtime.h>

typedef unsigned short u16;
typedef __attribute__((ext_vector_type(8))) short short8;
typedef __attribute__((ext_vector_type(4))) float f32x4;

#define MFMA16(a, b, c) __builtin_amdgcn_mfma_f32_16x16x32_bf16((a), (b), (c), 0, 0, 0)

__device__ __forceinline__ u16 f2bf(float f) {
    unsigned u = __float_as_uint(f);
    unsigned r = (u + 0x7FFFu + ((u >> 16) & 1u)) >> 16;
    return (u16)r;
}

__device__ const float MAXV[22] = {9.f, 1.f, 1.f, 10.f, 3.f, 254.f, 1.f, 1.f, 235.f, 8.f, 9.f,
                                   250.f, 29.f, 1.f, 1.f, 8.f, 1.f, 1.f, 6.f, 3.f, 1.f, 2.f};

// ---------------- prep: weights -> bf16, 1/MAX folded ----------------
__global__ void prep_kernel(
    const float* c1w, const float* c1b, const float* c2w, const float* c2b,
    const float* fcw, const float* fcb, const float* sfw, const float* sfb,
    const float* a0w, const float* a0b, const float* a1w, const float* a1b,
    const float* vw, const float* vb,
    u16* W1F, u16* W2T, u16* FCT, u16* SELFT, u16* HEADW, float* BIAS)
{
    int idx = blockIdx.x * 256 + threadIdx.x;
    if (idx < 73728) {                       // W1F frag layout (g*18+ks groups of 512)
        int grp = idx >> 9, off = idx & 511;
        int g = grp / 18, ks = grp - g * 18;
        int l = off >> 3, e = off & 7;
        int n = g * 16 + (l & 15);
        int k = ks * 32 + ((l >> 4) << 3) + e;
        float v = 0.f;
        if (k < 550) { int c = k / 25; v = c1w[n * 550 + k] * (1.0f / MAXV[c]); }
        W1F[idx] = f2bf(v);
    } else if (idx < 221184) {               // W2T [128][1152]: k = p*128 + ic
        int j = idx - 73728;
        int oc = j / 1152, k = j - oc * 1152;
        int p = k >> 7, ic = k & 127;
        W2T[j] = f2bf(c2w[oc * 1152 + ic * 9 + p]);
    } else if (idx < 253952) {               // FCT [256][128]
        int j = idx - 221184;
        FCT[j] = f2bf(fcw[j]);
    } else if (idx < 262144) {               // SELFT [256][32]
        int j = idx - 253952;
        int n = j >> 5, c = j & 31;
        float v = (c < 22) ? sfw[n * 22 + c] * (1.0f / MAXV[c]) : 0.f;
        SELFT[j] = f2bf(v);
    } else if (idx < 278528) {               // HEADW [32][512]
        int j = idx - 262144;
        int n = j >> 9, k = j & 511;
        float v = 0.f;
        if (n < 9) v = a0w[n * 512 + k];
        else if (n < 19) v = a1w[(n - 9) * 512 + k];
        else if (n == 19) v = vw[k];
        HEADW[j] = f2bf(v);
    } else if (idx < 279328) {               // BIAS[800]
        int j = idx - 278528;
        float v = 0.f;
        if (j < 128) v = c1b[j];
        else if (j < 256) v = c2b[j - 128];
        else if (j < 512) v = fcb[j - 256];
        else if (j < 768) v = sfb[j - 512];
        else {
            int j2 = j - 768;
            if (j2 < 9) v = a0b[j2]; else if (j2 < 19) v = a1b[j2 - 9]; else if (j2 == 19) v = vb[0];
        }
        BIAS[j] = v;
    }
}

// ---------------- K12: 4 samples/WG, 63KB LDS, 2 WGs/CU ----------------
// A [36][576] bf16 XOR-swizzled; B (conv1 weights) in registers (144 VGPR/wave).
// h1 layout: [sb=s/32][kcol=K/32][rb=s%32][e=K%32]  (K = pos*128 + col)
__global__ __launch_bounds__(256, 2) void k12_kernel(
    const int* __restrict__ obs, const u16* __restrict__ W1F,
    const float* __restrict__ BIAS, u16* __restrict__ h1, u16* __restrict__ s22g)
{
    __shared__ __align__(16) u16 A[36 * 576];     // 41,472 B
    __shared__ __align__(16) int box[2 * 2662];   // 21,296 B
    __shared__ u16 s22[128];
    const int tid = threadIdx.x, w = tid >> 6, l = tid & 63;
    const int s0 = blockIdx.x * 4;

    // prefetch obs: tid<200 -> sub = tid/100 (sample in pair), 2 tokens each
    int2 t0[3], t1[3];
    const int sub = tid / 100;
    const int tq = tid - sub * 100;
    if (tid < 200) {
        const int2* p0 = (const int2*)(obs + (long)(s0 + sub) * 600 + tq * 6);
        const int2* p1 = (const int2*)(obs + (long)(s0 + 2 + sub) * 600 + tq * 6);
        t0[0] = p0[0]; t0[1] = p0[1]; t0[2] = p0[2];
        t1[0] = p1[0]; t1[1] = p1[1]; t1[2] = p1[2];
    }

    // B fragments in regs (issued early, latency hidden under scatter)
    short8 bfr[2][18];
    #pragma unroll
    for (int nt = 0; nt < 2; ++nt)
        #pragma unroll
        for (int ks = 0; ks < 18; ++ks)
            bfr[nt][ks] = *(const short8*)(W1F + (((w * 2 + nt) * 18 + ks) << 9) + l * 8);

    {
        short8 z = {0, 0, 0, 0, 0, 0, 0, 0};
        for (int i = tid; i < 2592; i += 256) *(short8*)(A + i * 8) = z;
        int4 zz = {0, 0, 0, 0};
        for (int i = tid; i < 1331; i += 256) ((int4*)box)[i] = zz;
        if (tid < 128) s22[tid] = 0;
    }
    __syncthreads();

    int ce[2], en[2], va[2], xa[2], ya[2], aa[2], ok[2];

    #pragma unroll
    for (int ph = 0; ph < 2; ++ph) {
        if (tid < 200) {
            int raw[6];
            if (ph == 0) { raw[0]=t0[0].x; raw[1]=t0[0].y; raw[2]=t0[1].x; raw[3]=t0[1].y; raw[4]=t0[2].x; raw[5]=t0[2].y; }
            else         { raw[0]=t1[0].x; raw[1]=t1[0].y; raw[2]=t1[1].x; raw[3]=t1[1].y; raw[4]=t1[2].x; raw[5]=t1[2].y; }
            #pragma unroll
            for (int j = 0; j < 2; ++j) {
                int c = raw[j * 3], a = raw[j * 3 + 1], v = raw[j * 3 + 2];
                c = (c == 255) ? 0 : c; a = (a == 255) ? 0 : a; v = (v == 255) ? 0 : v;
                int xs = (c >> 4) & 15, ys = c & 15;
                ok[j] = ((unsigned)a < 22u) & (xs < 11) & (ys < 11);
                ce[j] = sub * 2662 + a * 121 + xs * 11 + ys;
                en[j] = ((tq * 2 + j) << 8) | (v & 255);
                va[j] = v; xa[j] = xs; ya[j] = ys; aa[j] = a;
                if (ok[j]) atomicMax(&box[ce[j]], en[j]);
            }
        }
        __syncthreads();
        if (tid < 200) {
            #pragma unroll
            for (int j = 0; j < 2; ++j) {
                if (ok[j] && box[ce[j]] == en[j]) {       // this token won the cell
                    u16 bv = f2bf((float)va[j]);
                    int ls = ph * 2 + sub;
                    if (xa[j] == 5 && ya[j] == 5) s22[ls * 32 + aa[j]] = bv;
                    int bcol = aa[j] * 25;
                    #pragma unroll
                    for (int ox = 0; ox < 3; ++ox) {
                        int kx = xa[j] - 3 * ox;
                        if ((unsigned)kx > 4u) continue;
                        #pragma unroll
                        for (int oy = 0; oy < 3; ++oy) {
                            int ky = ya[j] - 3 * oy;
                            if ((unsigned)ky > 4u) continue;
                            int row = ls * 9 + ox * 3 + oy;
                            int byte = ((row * 576 + bcol + kx * 5 + ky) << 1) ^ ((row & 7) << 4);
                            *(u16*)((char*)A + byte) = bv;
                        }
                    }
                }
            }
        }
        __syncthreads();
        if (ph == 0) {
            if (tid < 200) {                  // targeted box re-clear
                #pragma unroll
                for (int j = 0; j < 2; ++j) if (ok[j]) box[ce[j]] = 0;
            }
            __syncthreads();
        }
    }
    if (tid < 128) s22g[s0 * 32 + tid] = s22[tid];

    // ---- barrier-free GEMM: [48(36) x 576] x regs[576 x 32] per wave ----
    f32x4 acc[3][2];
    const f32x4 fz = {0.f, 0.f, 0.f, 0.f};
    #pragma unroll
    for (int i = 0; i < 3; ++i) { acc[i][0] = fz; acc[i][1] = fz; }

    #pragma unroll
    for (int ks = 0; ks < 18; ++ks) {
        short8 a[3];
        #pragma unroll
        for (int mt = 0; mt < 3; ++mt) {
            int row = mt * 16 + (l & 15);
            row = row < 36 ? row : 35;
            int off = ((row * 576 + ks * 32 + ((l >> 4) << 3)) << 1) ^ ((row & 7) << 4);
            a[mt] = *(const short8*)((const char*)A + off);
        }
        #pragma unroll
        for (int mt = 0; mt < 3; ++mt) {
            acc[mt][0] = MFMA16(a[mt], bfr[0][ks], acc[mt][0]);
            acc[mt][1] = MFMA16(a[mt], bfr[1][ks], acc[mt][1]);
        }
    }

    #pragma unroll
    for (int mt = 0; mt < 3; ++mt) {
        #pragma unroll
        for (int nt = 0; nt < 2; ++nt) {
            int col = w * 32 + nt * 16 + (l & 15);
            float bias = BIAS[col];
            int e = col & 31;                             // = nt*16 + (l&15)
            #pragma unroll
            for (int r = 0; r < 4; ++r) {
                int row = mt * 16 + ((l >> 4) << 2) + r;
                if (row < 36) {
                    int ls = row / 9;
                    int pos = row - ls * 9;
                    int s = s0 + ls;
                    float v = acc[mt][nt][r] + bias;
                    v = v > 0.f ? v : 0.f;
                    h1[(long)(s >> 5) * 36864 + (pos * 4 + w) * 1024 + (s & 31) * 32 + e] = f2bf(v);
                }
            }
        }
    }
}

// ---------------- K3: 32 samples/WG, 67.6KB LDS, 2 WGs/CU ----------------
union BbU {
    u16 c2[2][128 * 40];      // conv2 B chunks (K32, dbuf)   20,480 B
    u16 st[256 * 40];         // fc / self staging            20,480 B
    u16 hd[32 * 72];          // heads staging                 4,608 B
};

__global__ __launch_bounds__(256, 2) void k3_kernel(
    const u16* __restrict__ h1, const u16* __restrict__ s22g,
    const u16* __restrict__ W2T, const u16* __restrict__ FCT,
    const u16* __restrict__ SELFT, const u16* __restrict__ HEADW,
    const float* __restrict__ BIAS, float* __restrict__ out, int B)
{
    __shared__ __align__(16) u16 AbC[2][32 * 40];  //  5,120 B
    __shared__ __align__(16) BbU Bb;               // 20,480 B
    __shared__ __align__(16) u16 A3[32 * 136];     //  8,704 B
    __shared__ __align__(16) u16 HID[32 * 520];    // 33,280 B
    const int tid = threadIdx.x, w = tid >> 6, l = tid & 63;
    const int s0 = blockIdx.x * 32;
    const long hb = (long)blockIdx.x * 36864;
    const float* c2b = BIAS + 128;
    const float* fcb = BIAS + 256;
    const float* sfb = BIAS + 512;
    const float* hdb = BIAS + 768;
    const f32x4 fz = {0.f, 0.f, 0.f, 0.f};

    // ---- conv2: M=32, N=128, K=1152 in 36 K32 chunks, dbuf, 1 barrier/chunk ----
    f32x4 acc4[2][2];
    acc4[0][0] = fz; acc4[0][1] = fz; acc4[1][0] = fz; acc4[1][1] = fz;

    short8 arg_;                   // A chunk (tid<128): 2KB contiguous, coalesced
    short8 brg[2];                 // B chunk: 512 slots (oc, seg)
    if (tid < 128) arg_ = *(const short8*)(h1 + hb + tid * 8);
    #pragma unroll
    for (int q = 0; q < 2; ++q) {
        int s = tid + q * 256;
        brg[q] = *(const short8*)(W2T + (s >> 2) * 1152 + (s & 3) * 8);
    }
    if (tid < 128) *(short8*)(AbC[0] + (tid >> 2) * 40 + (tid & 3) * 8) = arg_;
    #pragma unroll
    for (int q = 0; q < 2; ++q) {
        int s = tid + q * 256;
        *(short8*)(Bb.c2[0] + (s >> 2) * 40 + (s & 3) * 8) = brg[q];
    }
    __syncthreads();

    for (int kc = 0; kc < 36; ++kc) {
        if (kc < 35) {
            if (tid < 128) arg_ = *(const short8*)(h1 + hb + (kc + 1) * 1024 + tid * 8);
            #pragma unroll
            for (int q = 0; q < 2; ++q) {
                int s = tid + q * 256;
                brg[q] = *(const short8*)(W2T + (s >> 2) * 1152 + (kc + 1) * 32 + (s & 3) * 8);
            }
        }
        const int cur = kc & 1;
        short8 b0 = *(const short8*)(Bb.c2[cur] + (w * 32 + (l & 15)) * 40 + ((l >> 4) << 3));
        short8 b1 = *(const short8*)(Bb.c2[cur] + (w * 32 + 16 + (l & 15)) * 40 + ((l >> 4) << 3));
        short8 a0 = *(const short8*)(AbC[cur] + ((l & 15)) * 40 + ((l >> 4) << 3));
        short8 a1 = *(const short8*)(AbC[cur] + (16 + (l & 15)) * 40 + ((l >> 4) << 3));
        acc4[0][0] = MFMA16(a0, b0, acc4[0][0]);
        acc4[0][1] = MFMA16(a0, b1, acc4[0][1]);
        acc4[1][0] = MFMA16(a1, b0, acc4[1][0]);
        acc4[1][1] = MFMA16(a1, b1, acc4[1][1]);
        if (kc < 35) {
            if (tid < 128) *(short8*)(AbC[cur ^ 1] + (tid >> 2) * 40 + (tid & 3) * 8) = arg_;
            #pragma unroll
            for (int q = 0; q < 2; ++q) {
                int s = tid + q * 256;
                *(short8*)(Bb.c2[cur ^ 1] + (s >> 2) * 40 + (s & 3) * 8) = brg[q];
            }
        }
        __syncthreads();
    }
    {
        #pragma unroll
        for (int mt = 0; mt < 2; ++mt)
            #pragma unroll
            for (int nt = 0; nt < 2; ++nt) {
                int col = w * 32 + nt * 16 + (l & 15);
                float bias = c2b[col];
                #pragma unroll
                for (int r = 0; r < 4; ++r) {
                    int row = mt * 16 + ((l >> 4) << 2) + r;
                    float v = acc4[mt][nt][r] + bias; v = v > 0.f ? v : 0.f;
                    A3[row * 136 + col] = f2bf(v);
                }
            }
    }

    // ---- fc: M=32, N=256, K=128 in 4 K32 chunks; single-buffer staged ----
    f32x4 acc8[2][4];
    #pragma unroll
    for (int i = 0; i < 2; ++i)
        #pragma unroll
        for (int j = 0; j < 4; ++j) acc8[i][j] = fz;
    short8 fr[4];
    #pragma unroll
    for (int q = 0; q < 4; ++q) {
        int s = tid + q * 256;
        fr[q] = *(const short8*)(FCT + (s >> 2) * 128 + (s & 3) * 8);
    }
    for (int kc = 0; kc < 4; ++kc) {
        __syncthreads();                       // prev reads done (also guards A3 writes at kc=0)
        #pragma unroll
        for (int q = 0; q < 4; ++q) {
            int s = tid + q * 256;
            *(short8*)(Bb.st + (s >> 2) * 40 + (s & 3) * 8) = fr[q];
        }
        __syncthreads();
        if (kc < 3) {
            #pragma unroll
            for (int q = 0; q < 4; ++q) {
                int s = tid + q * 256;
                fr[q] = *(const short8*)(FCT + (s >> 2) * 128 + (kc + 1) * 32 + (s & 3) * 8);
            }
        }
        short8 bv[4];
        #pragma unroll
        for (int nt = 0; nt < 4; ++nt)
            bv[nt] = *(const short8*)(Bb.st + (w * 64 + nt * 16 + (l & 15)) * 40 + ((l >> 4) << 3));
        #pragma unroll
        for (int mt = 0; mt < 2; ++mt) {
            short8 a = *(const short8*)(A3 + (mt * 16 + (l & 15)) * 136 + kc * 32 + ((l >> 4) << 3));
            #pragma unroll
            for (int nt = 0; nt < 4; ++nt) acc8[mt][nt] = MFMA16(a, bv[nt], acc8[mt][nt]);
        }
    }
    {
        #pragma unroll
        for (int mt = 0; mt < 2; ++mt)
            #pragma unroll
            for (int nt = 0; nt < 4; ++nt) {
                int col = w * 64 + nt * 16 + (l & 15);
                float bias = fcb[col];
                #pragma unroll
                for (int r = 0; r < 4; ++r) {
                    int row = mt * 16 + ((l >> 4) << 2) + r;
                    float v = acc8[mt][nt][r] + bias; v = v > 0.f ? v : 0.f;
                    HID[row * 520 + 256 + col] = f2bf(v);
                }
            }
    }
    __syncthreads();                           // fc Bb reads done; HID(256+) written

    // ---- self: s22[32][32] @ SELFT[256][32] -> HID cols 0..255 ----
    if (tid < 128) {
        short8 sv = *(const short8*)(s22g + (s0 + (tid >> 2)) * 32 + (tid & 3) * 8);
        *(short8*)(AbC[0] + (tid >> 2) * 40 + (tid & 3) * 8) = sv;
    }
    #pragma unroll
    for (int q = 0; q < 4; ++q) {
        int s = tid + q * 256;
        short8 sv = *(const short8*)(SELFT + (s >> 2) * 32 + (s & 3) * 8);
        *(short8*)(Bb.st + (s >> 2) * 40 + (s & 3) * 8) = sv;
    }
    __syncthreads();
    {
        #pragma unroll
        for (int i = 0; i < 2; ++i)
            #pragma unroll
            for (int j = 0; j < 4; ++j) acc8[i][j] = fz;
        short8 bv[4];
        #pragma unroll
        for (int nt = 0; nt < 4; ++nt)
            bv[nt] = *(const short8*)(Bb.st + (w * 64 + nt * 16 + (l & 15)) * 40 + ((l >> 4) << 3));
        #pragma unroll
        for (int mt = 0; mt < 2; ++mt) {
            short8 a = *(const short8*)(AbC[0] + (mt * 16 + (l & 15)) * 40 + ((l >> 4) << 3));
            #pragma unroll
            for (int nt = 0; nt < 4; ++nt) acc8[mt][nt] = MFMA16(a, bv[nt], acc8[mt][nt]);
        }
        #pragma unroll
        for (int mt = 0; mt < 2; ++mt)
            #pragma unroll
            for (int nt = 0; nt < 4; ++nt) {
                int col = w * 64 + nt * 16 + (l & 15);
                float bias = sfb[col];
                #pragma unroll
                for (int r = 0; r < 4; ++r) {
                    int row = mt * 16 + ((l >> 4) << 2) + r;
                    float v = acc8[mt][nt][r] + bias; v = v > 0.f ? v : 0.f;
                    HID[row * 520 + col] = f2bf(v);
                }
            }
    }

    // ---- heads: HID[32][512] @ HEADW[32][512]; wave w: rows (w&1)*16.., cols (w>>1)*16.. ----
    f32x4 hacc = fz;
    const int rt = w & 1, ct = w >> 1;
    short8 hr = *(const short8*)(HEADW + (tid >> 3) * 512 + (tid & 7) * 8);
    for (int kc = 0; kc < 8; ++kc) {
        __syncthreads();                       // prev reads done (guards self HID writes at kc=0)
        *(short8*)(Bb.hd + (tid >> 3) * 72 + (tid & 7) * 8) = hr;
        __syncthreads();
        if (kc < 7) hr = *(const short8*)(HEADW + (tid >> 3) * 512 + (kc + 1) * 64 + (tid & 7) * 8);
        #pragma unroll
        for (int ks = 0; ks < 2; ++ks) {
            short8 a = *(const short8*)(HID + (rt * 16 + (l & 15)) * 520 + kc * 64 + ks * 32 + ((l >> 4) << 3));
            short8 b = *(const short8*)(Bb.hd + (ct * 16 + (l & 15)) * 72 + ks * 32 + ((l >> 4) << 3));
            hacc = MFMA16(a, b, hacc);
        }
    }
    #pragma unroll
    for (int r = 0; r < 4; ++r) {
        int srow = s0 + rt * 16 + ((l >> 4) << 2) + r;
        int col = ct * 16 + (l & 15);
        float v = hacc[r] + hdb[col];
        if (col < 9) out[(long)srow * 9 + col] = v;
        else if (col < 19) out[(long)B * 9 + (long)srow * 10 + (col - 9)] = v;
        else if (col == 19) out[(long)B * 19 + srow] = v;
    }
}

extern "C" void kernel_launch(void* const* d_in, const int* in_sizes, int n_in,
                              void* d_out, int out_size, void* d_ws, size_t ws_size,
                              hipStream_t stream)
{
    const int*   obs = (const int*)d_in[0];
    const float* c1w = (const float*)d_in[1];
    const float* c1b = (const float*)d_in[2];
    const float* c2w = (const float*)d_in[3];
    const float* c2b = (const float*)d_in[4];
    const float* fcw = (const float*)d_in[5];
    const float* fcb = (const float*)d_in[6];
    const float* sfw = (const float*)d_in[7];
    const float* sfb = (const float*)d_in[8];
    const float* a0w = (const float*)d_in[9];
    const float* a0b = (const float*)d_in[10];
    const float* a1w = (const float*)d_in[11];
    const float* a1b = (const float*)d_in[12];
    const float* vw  = (const float*)d_in[13];
    const float* vb  = (const float*)d_in[14];
    const int B = in_sizes[0] / 600;   // 16384

    char* ws = (char*)d_ws;
    u16*   W1F   = (u16*)(ws + 0);
    u16*   W2T   = (u16*)(ws + 147456);
    u16*   FCT   = (u16*)(ws + 442368);
    u16*   SELFT = (u16*)(ws + 507904);
    u16*   HEADW = (u16*)(ws + 524288);
    float* BIAS  = (float*)(ws + 557056);
    u16*   s22g  = (u16*)(ws + 560256);
    u16*   h1    = (u16*)(ws + 560256 + (size_t)B * 64);

    prep_kernel<<<1092, 256, 0, stream>>>(c1w, c1b, c2w, c2b, fcw, fcb, sfw, sfb,
                                          a0w, a0b, a1w, a1b, vw, vb,
                                          W1F, W2T, FCT, SELFT, HEADW, BIAS);
    k12_kernel<<<B / 4, 256, 0, stream>>>(obs, W1F, BIAS, h1, s22g);
    k3_kernel<<<B / 32, 256, 0, stream>>>(h1, s22g, W2T, FCT, SELFT, HEADW, BIAS,
                                          (float*)d_out, B);
}

// Round 6
// 81.757 us; speedup vs baseline: 5.6916x; 1.2003x over previous
//
#include <hip/hip_runtime.h>

typedef unsigned short u16;
typedef __attribute__((ext_vector_type(8))) short short8;
typedef __attribute__((ext_vector_type(4))) float f32x4;

#define MFMA16(a, b, c) __builtin_amdgcn_mfma_f32_16x16x32_bf16((a), (b), (c), 0, 0, 0)

__device__ __forceinline__ u16 f2bf(float f) {
    unsigned u = __float_as_uint(f);
    unsigned r = (u + 0x7FFFu + ((u >> 16) & 1u)) >> 16;
    return (u16)r;
}

__device__ const float MAXV[22] = {9.f, 1.f, 1.f, 10.f, 3.f, 254.f, 1.f, 1.f, 235.f, 8.f, 9.f,
                                   250.f, 29.f, 1.f, 1.f, 8.f, 1.f, 1.f, 6.f, 3.f, 1.f, 2.f};

// ---------------- prep: weights -> bf16, 1/MAX folded ----------------
__global__ void prep_kernel(
    const float* c1w, const float* c1b, const float* c2w, const float* c2b,
    const float* fcw, const float* fcb, const float* sfw, const float* sfb,
    const float* a0w, const float* a0b, const float* a1w, const float* a1b,
    const float* vw, const float* vb,
    u16* W1F, u16* W2T, u16* FCT, u16* SELFT, u16* HEADW, float* BIAS)
{
    int idx = blockIdx.x * 256 + threadIdx.x;
    if (idx < 73728) {                       // W1F frag layout (g*18+ks groups of 512)
        int grp = idx >> 9, off = idx & 511;
        int g = grp / 18, ks = grp - g * 18;
        int l = off >> 3, e = off & 7;
        int n = g * 16 + (l & 15);
        int k = ks * 32 + ((l >> 4) << 3) + e;
        float v = 0.f;
        if (k < 550) { int c = k / 25; v = c1w[n * 550 + k] * (1.0f / MAXV[c]); }
        W1F[idx] = f2bf(v);
    } else if (idx < 221184) {               // W2T [128][1152]: k = p*128 + ic
        int j = idx - 73728;
        int oc = j / 1152, k = j - oc * 1152;
        int p = k >> 7, ic = k & 127;
        W2T[j] = f2bf(c2w[oc * 1152 + ic * 9 + p]);
    } else if (idx < 253952) {               // FCT [256][128]
        int j = idx - 221184;
        FCT[j] = f2bf(fcw[j]);
    } else if (idx < 262144) {               // SELFT [256][32]
        int j = idx - 253952;
        int n = j >> 5, c = j & 31;
        float v = (c < 22) ? sfw[n * 22 + c] * (1.0f / MAXV[c]) : 0.f;
        SELFT[j] = f2bf(v);
    } else if (idx < 278528) {               // HEADW [32][512]
        int j = idx - 262144;
        int n = j >> 9, k = j & 511;
        float v = 0.f;
        if (n < 9) v = a0w[n * 512 + k];
        else if (n < 19) v = a1w[(n - 9) * 512 + k];
        else if (n == 19) v = vw[k];
        HEADW[j] = f2bf(v);
    } else if (idx < 279328) {               // BIAS[800]
        int j = idx - 278528;
        float v = 0.f;
        if (j < 128) v = c1b[j];
        else if (j < 256) v = c2b[j - 128];
        else if (j < 512) v = fcb[j - 256];
        else if (j < 768) v = sfb[j - 512];
        else {
            int j2 = j - 768;
            if (j2 < 9) v = a0b[j2]; else if (j2 < 19) v = a1b[j2 - 9]; else if (j2 == 19) v = vb[0];
        }
        BIAS[j] = v;
    }
}

// ---------------- K12: 4 samples/WG, 52.4KB LDS, 3 WGs/CU ----------------
// Scatter: 4 single-sample phases, box[2664] ints, enc+1 trick (winner clears cell, no sweep).
// GEMM: A [36][576] XOR-swizzled in LDS, B loaded per-k-slot from W1F (L2-hot).
// Store: repack acc into LDS (A region) then coalesced short8 stores.
// h1 layout: [sb=s/32][kcol=pos*4+w][rb=s%32][e]  (K = pos*128 + col, col = w*32+e)
__global__ __launch_bounds__(256, 3) void k12_kernel(
    const int* __restrict__ obs, const u16* __restrict__ W1F,
    const float* __restrict__ BIAS, u16* __restrict__ h1, u16* __restrict__ s22g)
{
    __shared__ __align__(16) u16 A[36 * 576];     // 41,472 B
    __shared__ __align__(16) int box[2664];       // 10,656 B
    __shared__ u16 s22[128];
    const int tid = threadIdx.x, w = tid >> 6, l = tid & 63;
    const int s0 = blockIdx.x * 4;

    // prefetch all 4 samples' tokens (1 token per thread per phase)
    int tok[4][3];
    if (tid < 200) {
        #pragma unroll
        for (int p = 0; p < 4; ++p) {
            const int* tp = obs + (long)(s0 + p) * 600 + tid * 3;
            tok[p][0] = tp[0]; tok[p][1] = tp[1]; tok[p][2] = tp[2];
        }
    }

    {   // zero A + box + s22
        short8 z = {0, 0, 0, 0, 0, 0, 0, 0};
        for (int i = tid; i < 2592; i += 256) *(short8*)(A + i * 8) = z;
        int4 zz = {0, 0, 0, 0};
        for (int i = tid; i < 666; i += 256) ((int4*)box)[i] = zz;
        if (tid < 128) s22[tid] = 0;
    }
    __syncthreads();

    #pragma unroll
    for (int p = 0; p < 4; ++p) {
        int ce = 0, en = 0, va = 0, xa = 0, ya = 0, aa = 0, ok = 0;
        if (tid < 200) {
            int c = tok[p][0], a = tok[p][1], v = tok[p][2];
            c = (c == 255) ? 0 : c; a = (a == 255) ? 0 : a; v = (v == 255) ? 0 : v;
            int xs = (c >> 4) & 15, ys = c & 15;
            ok = ((unsigned)a < 22u) & (xs < 11) & (ys < 11);
            ce = a * 121 + xs * 11 + ys;
            en = ((tid << 8) | (v & 255)) + 1;            // never 0
            va = v; xa = xs; ya = ys; aa = a;
            if (ok) atomicMax(&box[ce], en);
        }
        __syncthreads();                                  // all atomics visible
        if (ok && box[ce] == en) {                        // this token won the cell
            box[ce] = 0;                                  // self-clear for next phase
            u16 bv = f2bf((float)va);
            if (xa == 5 && ya == 5) s22[p * 32 + aa] = bv;
            int bcol = aa * 25;
            #pragma unroll
            for (int ox = 0; ox < 3; ++ox) {
                int kx = xa - 3 * ox;
                if ((unsigned)kx > 4u) continue;
                #pragma unroll
                for (int oy = 0; oy < 3; ++oy) {
                    int ky = ya - 3 * oy;
                    if ((unsigned)ky > 4u) continue;
                    int row = p * 9 + ox * 3 + oy;
                    int byte = ((row * 576 + bcol + kx * 5 + ky) << 1) ^ ((row & 7) << 4);
                    *(u16*)((char*)A + byte) = bv;
                }
            }
        }
        __syncthreads();                                  // rechecks+clears done
    }
    if (tid < 128) s22g[s0 * 32 + tid] = s22[tid];

    // ---- GEMM: [48(36) x 576] x [576 x 32 per wave], B per-slot from L2 ----
    f32x4 acc[3][2];
    const f32x4 fz = {0.f, 0.f, 0.f, 0.f};
    #pragma unroll
    for (int i = 0; i < 3; ++i) { acc[i][0] = fz; acc[i][1] = fz; }

    #pragma unroll
    for (int ks = 0; ks < 18; ++ks) {
        short8 b0 = *(const short8*)(W1F + (((w * 2 + 0) * 18 + ks) << 9) + l * 8);
        short8 b1 = *(const short8*)(W1F + (((w * 2 + 1) * 18 + ks) << 9) + l * 8);
        short8 a[3];
        #pragma unroll
        for (int mt = 0; mt < 3; ++mt) {
            int row = mt * 16 + (l & 15);
            row = row < 36 ? row : 35;
            int off = ((row * 576 + ks * 32 + ((l >> 4) << 3)) << 1) ^ ((row & 7) << 4);
            a[mt] = *(const short8*)((const char*)A + off);
        }
        #pragma unroll
        for (int mt = 0; mt < 3; ++mt) {
            acc[mt][0] = MFMA16(a[mt], b0, acc[mt][0]);
            acc[mt][1] = MFMA16(a[mt], b1, acc[mt][1]);
        }
    }

    __syncthreads();                       // all A reads done; reuse A region for repack
    u16* R = (u16*)A;                      // R[kcol*128 + ls*32 + e], 4608 u16
    #pragma unroll
    for (int mt = 0; mt < 3; ++mt) {
        #pragma unroll
        for (int nt = 0; nt < 2; ++nt) {
            int col = w * 32 + nt * 16 + (l & 15);
            float bias = BIAS[col];
            int e = nt * 16 + (l & 15);
            #pragma unroll
            for (int r = 0; r < 4; ++r) {
                int row = mt * 16 + ((l >> 4) << 2) + r;
                if (row < 36) {
                    int ls = row / 9;
                    int pos = row - ls * 9;
                    float v = acc[mt][nt][r] + bias;
                    v = v > 0.f ? v : 0.f;
                    R[(pos * 4 + w) * 128 + ls * 32 + e] = f2bf(v);
                }
            }
        }
    }
    __syncthreads();
    {   // coalesced store: 576 short8 slots; slot = kcol*16 + rem
        const long gbase = (long)(s0 >> 5) * 36864 + (long)(s0 & 31) * 32;
        #pragma unroll
        for (int q = 0; q < 3; ++q) {
            int slot = tid + q * 256;
            if (slot < 576) {
                int kcol = slot >> 4, rem = slot & 15;
                *(short8*)(h1 + gbase + kcol * 1024 + rem * 8) = *(const short8*)(R + slot * 8);
            }
        }
    }
}

// ---------------- K3: 32 samples/WG, 67.6KB LDS, 2 WGs/CU ----------------
union BbU {
    u16 c2[2][128 * 40];      // conv2 B chunks (K32, dbuf)   20,480 B
    u16 st[256 * 40];         // fc / self / heads staging
};

__global__ __launch_bounds__(256, 2) void k3_kernel(
    const u16* __restrict__ h1, const u16* __restrict__ s22g,
    const u16* __restrict__ W2T, const u16* __restrict__ FCT,
    const u16* __restrict__ SELFT, const u16* __restrict__ HEADW,
    const float* __restrict__ BIAS, float* __restrict__ out, int B)
{
    __shared__ __align__(16) u16 AbC[2][32 * 40];  //  5,120 B
    __shared__ __align__(16) BbU Bb;               // 20,480 B
    __shared__ __align__(16) u16 A3[32 * 136];     //  8,704 B
    __shared__ __align__(16) u16 HID[32 * 520];    // 33,280 B
    const int tid = threadIdx.x, w = tid >> 6, l = tid & 63;
    const int s0 = blockIdx.x * 32;
    const long hb = (long)blockIdx.x * 36864;
    const float* c2b = BIAS + 128;
    const float* fcb = BIAS + 256;
    const float* sfb = BIAS + 512;
    const float* hdb = BIAS + 768;
    const f32x4 fz = {0.f, 0.f, 0.f, 0.f};

    // ---- conv2: M=32, N=128, K=1152 in 36 K32 chunks, dbuf, 1 barrier/chunk ----
    f32x4 acc4[2][2];
    acc4[0][0] = fz; acc4[0][1] = fz; acc4[1][0] = fz; acc4[1][1] = fz;

    short8 arg_;                   // A chunk (tid<128): 2KB contiguous, coalesced
    short8 brg[2];                 // B chunk
    if (tid < 128) arg_ = *(const short8*)(h1 + hb + tid * 8);
    #pragma unroll
    for (int q = 0; q < 2; ++q) {
        int s = tid + q * 256;
        brg[q] = *(const short8*)(W2T + (s >> 2) * 1152 + (s & 3) * 8);
    }
    if (tid < 128) *(short8*)(AbC[0] + (tid >> 2) * 40 + (tid & 3) * 8) = arg_;
    #pragma unroll
    for (int q = 0; q < 2; ++q) {
        int s = tid + q * 256;
        *(short8*)(Bb.c2[0] + (s >> 2) * 40 + (s & 3) * 8) = brg[q];
    }
    __syncthreads();

    for (int kc = 0; kc < 36; ++kc) {
        if (kc < 35) {
            if (tid < 128) arg_ = *(const short8*)(h1 + hb + (kc + 1) * 1024 + tid * 8);
            #pragma unroll
            for (int q = 0; q < 2; ++q) {
                int s = tid + q * 256;
                brg[q] = *(const short8*)(W2T + (s >> 2) * 1152 + (kc + 1) * 32 + (s & 3) * 8);
            }
        }
        const int cur = kc & 1;
        short8 b0 = *(const short8*)(Bb.c2[cur] + (w * 32 + (l & 15)) * 40 + ((l >> 4) << 3));
        short8 b1 = *(const short8*)(Bb.c2[cur] + (w * 32 + 16 + (l & 15)) * 40 + ((l >> 4) << 3));
        short8 a0 = *(const short8*)(AbC[cur] + ((l & 15)) * 40 + ((l >> 4) << 3));
        short8 a1 = *(const short8*)(AbC[cur] + (16 + (l & 15)) * 40 + ((l >> 4) << 3));
        acc4[0][0] = MFMA16(a0, b0, acc4[0][0]);
        acc4[0][1] = MFMA16(a0, b1, acc4[0][1]);
        acc4[1][0] = MFMA16(a1, b0, acc4[1][0]);
        acc4[1][1] = MFMA16(a1, b1, acc4[1][1]);
        if (kc < 35) {
            if (tid < 128) *(short8*)(AbC[cur ^ 1] + (tid >> 2) * 40 + (tid & 3) * 8) = arg_;
            #pragma unroll
            for (int q = 0; q < 2; ++q) {
                int s = tid + q * 256;
                *(short8*)(Bb.c2[cur ^ 1] + (s >> 2) * 40 + (s & 3) * 8) = brg[q];
            }
        }
        __syncthreads();
    }
    {
        #pragma unroll
        for (int mt = 0; mt < 2; ++mt)
            #pragma unroll
            for (int nt = 0; nt < 2; ++nt) {
                int col = w * 32 + nt * 16 + (l & 15);
                float bias = c2b[col];
                #pragma unroll
                for (int r = 0; r < 4; ++r) {
                    int row = mt * 16 + ((l >> 4) << 2) + r;
                    float v = acc4[mt][nt][r] + bias; v = v > 0.f ? v : 0.f;
                    A3[row * 136 + col] = f2bf(v);
                }
            }
    }

    // ---- fc: M=32, N=256, K=128 in 4 K32 chunks ----
    f32x4 acc8[2][4];
    #pragma unroll
    for (int i = 0; i < 2; ++i)
        #pragma unroll
        for (int j = 0; j < 4; ++j) acc8[i][j] = fz;
    short8 fr[4];
    #pragma unroll
    for (int q = 0; q < 4; ++q) {
        int s = tid + q * 256;
        fr[q] = *(const short8*)(FCT + (s >> 2) * 128 + (s & 3) * 8);
    }
    for (int kc = 0; kc < 4; ++kc) {
        __syncthreads();
        #pragma unroll
        for (int q = 0; q < 4; ++q) {
            int s = tid + q * 256;
            *(short8*)(Bb.st + (s >> 2) * 40 + (s & 3) * 8) = fr[q];
        }
        __syncthreads();
        if (kc < 3) {
            #pragma unroll
            for (int q = 0; q < 4; ++q) {
                int s = tid + q * 256;
                fr[q] = *(const short8*)(FCT + (s >> 2) * 128 + (kc + 1) * 32 + (s & 3) * 8);
            }
        }
        short8 bv[4];
        #pragma unroll
        for (int nt = 0; nt < 4; ++nt)
            bv[nt] = *(const short8*)(Bb.st + (w * 64 + nt * 16 + (l & 15)) * 40 + ((l >> 4) << 3));
        #pragma unroll
        for (int mt = 0; mt < 2; ++mt) {
            short8 a = *(const short8*)(A3 + (mt * 16 + (l & 15)) * 136 + kc * 32 + ((l >> 4) << 3));
            #pragma unroll
            for (int nt = 0; nt < 4; ++nt) acc8[mt][nt] = MFMA16(a, bv[nt], acc8[mt][nt]);
        }
    }
    {
        #pragma unroll
        for (int mt = 0; mt < 2; ++mt)
            #pragma unroll
            for (int nt = 0; nt < 4; ++nt) {
                int col = w * 64 + nt * 16 + (l & 15);
                float bias = fcb[col];
                #pragma unroll
                for (int r = 0; r < 4; ++r) {
                    int row = mt * 16 + ((l >> 4) << 2) + r;
                    float v = acc8[mt][nt][r] + bias; v = v > 0.f ? v : 0.f;
                    HID[row * 520 + 256 + col] = f2bf(v);
                }
            }
    }
    __syncthreads();

    // ---- self: s22[32][32] @ SELFT[256][32] -> HID cols 0..255 ----
    if (tid < 128) {
        short8 sv = *(const short8*)(s22g + (s0 + (tid >> 2)) * 32 + (tid & 3) * 8);
        *(short8*)(AbC[0] + (tid >> 2) * 40 + (tid & 3) * 8) = sv;
    }
    #pragma unroll
    for (int q = 0; q < 4; ++q) {
        int s = tid + q * 256;
        short8 sv = *(const short8*)(SELFT + (s >> 2) * 32 + (s & 3) * 8);
        *(short8*)(Bb.st + (s >> 2) * 40 + (s & 3) * 8) = sv;
    }
    __syncthreads();
    {
        #pragma unroll
        for (int i = 0; i < 2; ++i)
            #pragma unroll
            for (int j = 0; j < 4; ++j) acc8[i][j] = fz;
        short8 bv[4];
        #pragma unroll
        for (int nt = 0; nt < 4; ++nt)
            bv[nt] = *(const short8*)(Bb.st + (w * 64 + nt * 16 + (l & 15)) * 40 + ((l >> 4) << 3));
        #pragma unroll
        for (int mt = 0; mt < 2; ++mt) {
            short8 a = *(const short8*)(AbC[0] + (mt * 16 + (l & 15)) * 40 + ((l >> 4) << 3));
            #pragma unroll
            for (int nt = 0; nt < 4; ++nt) acc8[mt][nt] = MFMA16(a, bv[nt], acc8[mt][nt]);
        }
        #pragma unroll
        for (int mt = 0; mt < 2; ++mt)
            #pragma unroll
            for (int nt = 0; nt < 4; ++nt) {
                int col = w * 64 + nt * 16 + (l & 15);
                float bias = sfb[col];
                #pragma unroll
                for (int r = 0; r < 4; ++r) {
                    int row = mt * 16 + ((l >> 4) << 2) + r;
                    float v = acc8[mt][nt][r] + bias; v = v > 0.f ? v : 0.f;
                    HID[row * 520 + col] = f2bf(v);
                }
            }
    }

    // ---- heads: HID[32][512] @ HEADW[32][512], staged in 2 halves of K=256 ----
    f32x4 hacc = fz;
    const int rt = w & 1, ct = w >> 1;
    #pragma unroll
    for (int half = 0; half < 2; ++half) {
        __syncthreads();                       // prior Bb/HID uses done
        #pragma unroll
        for (int q = 0; q < 4; ++q) {
            int s2 = tid + q * 256;            // row = s2>>5 (0..31), seg = s2&31
            *(short8*)(Bb.st + (s2 >> 5) * 264 + (s2 & 31) * 8) =
                *(const short8*)(HEADW + (s2 >> 5) * 512 + half * 256 + (s2 & 31) * 8);
        }
        __syncthreads();
        #pragma unroll
        for (int kc = 0; kc < 4; ++kc)
            #pragma unroll
            for (int ks = 0; ks < 2; ++ks) {
                int koff = kc * 64 + ks * 32;
                short8 a = *(const short8*)(HID + (rt * 16 + (l & 15)) * 520 + half * 256 + koff + ((l >> 4) << 3));
                short8 b = *(const short8*)(Bb.st + (ct * 16 + (l & 15)) * 264 + koff + ((l >> 4) << 3));
                hacc = MFMA16(a, b, hacc);
            }
    }
    #pragma unroll
    for (int r = 0; r < 4; ++r) {
        int srow = s0 + rt * 16 + ((l >> 4) << 2) + r;
        int col = ct * 16 + (l & 15);
        float v = hacc[r] + hdb[col];
        if (col < 9) out[(long)srow * 9 + col] = v;
        else if (col < 19) out[(long)B * 9 + (long)srow * 10 + (col - 9)] = v;
        else if (col == 19) out[(long)B * 19 + srow] = v;
    }
}

extern "C" void kernel_launch(void* const* d_in, const int* in_sizes, int n_in,
                              void* d_out, int out_size, void* d_ws, size_t ws_size,
                              hipStream_t stream)
{
    const int*   obs = (const int*)d_in[0];
    const float* c1w = (const float*)d_in[1];
    const float* c1b = (const float*)d_in[2];
    const float* c2w = (const float*)d_in[3];
    const float* c2b = (const float*)d_in[4];
    const float* fcw = (const float*)d_in[5];
    const float* fcb = (const float*)d_in[6];
    const float* sfw = (const float*)d_in[7];
    const float* sfb = (const float*)d_in[8];
    const float* a0w = (const float*)d_in[9];
    const float* a0b = (const float*)d_in[10];
    const float* a1w = (const float*)d_in[11];
    const float* a1b = (const float*)d_in[12];
    const float* vw  = (const float*)d_in[13];
    const float* vb  = (const float*)d_in[14];
    const int B = in_sizes[0] / 600;   // 16384

    char* ws = (char*)d_ws;
    u16*   W1F   = (u16*)(ws + 0);
    u16*   W2T   = (u16*)(ws + 147456);
    u16*   FCT   = (u16*)(ws + 442368);
    u16*   SELFT = (u16*)(ws + 507904);
    u16*   HEADW = (u16*)(ws + 524288);
    float* BIAS  = (float*)(ws + 557056);
    u16*   s22g  = (u16*)(ws + 560256);
    u16*   h1    = (u16*)(ws + 560256 + (size_t)B * 64);

    prep_kernel<<<1092, 256, 0, stream>>>(c1w, c1b, c2w, c2b, fcw, fcb, sfw, sfb,
                                          a0w, a0b, a1w, a1b, vw, vb,
                                          W1F, W2T, FCT, SELFT, HEADW, BIAS);
    k12_kernel<<<B / 4, 256, 0, stream>>>(obs, W1F, BIAS, h1, s22g);
    k3_kernel<<<B / 32, 256, 0, stream>>>(h1, s22g, W2T, FCT, SELFT, HEADW, BIAS,
                                          (float*)d_out, B);
}

// Round 7
// 75.941 us; speedup vs baseline: 6.1275x; 1.0766x over previous
//
#include <hip/hip_runtime.h>

typedef unsigned short u16;
typedef __attribute__((ext_vector_type(8))) short short8;
typedef __attribute__((ext_vector_type(4))) float f32x4;

#define MFMA16(a, b, c) __builtin_amdgcn_mfma_f32_16x16x32_bf16((a), (b), (c), 0, 0, 0)

__device__ __forceinline__ u16 f2bf(float f) {
    unsigned u = __float_as_uint(f);
    unsigned r = (u + 0x7FFFu + ((u >> 16) & 1u)) >> 16;
    return (u16)r;
}

__device__ const float MAXV[22] = {9.f, 1.f, 1.f, 10.f, 3.f, 254.f, 1.f, 1.f, 235.f, 8.f, 9.f,
                                   250.f, 29.f, 1.f, 1.f, 8.f, 1.f, 1.f, 6.f, 3.f, 1.f, 2.f};

// ---------------- prep: all weights -> bf16 MFMA-fragment layouts, 1/MAX folded ----------------
// Fragment layout rule: FRAG[(grp)*512 + l*8 + e] = W[n = n0(grp)*16 + (l&15)][k = k0(grp)*32 + (l>>4)*8 + e]
__global__ void prep_kernel(
    const float* c1w, const float* c1b, const float* c2w, const float* c2b,
    const float* fcw, const float* fcb, const float* sfw, const float* sfb,
    const float* a0w, const float* a0b, const float* a1w, const float* a1b,
    const float* vw, const float* vb,
    u16* W1F, u16* W2F, u16* FCF, u16* SELFF, u16* HEADF, float* BIAS)
{
    int idx = blockIdx.x * 256 + threadIdx.x;
    if (idx < 73728) {                       // W1F: grp = g*18+ks, g=oc/16, ks=K/32 (K=576)
        int grp = idx >> 9, off = idx & 511;
        int g = grp / 18, ks = grp - g * 18;
        int l = off >> 3, e = off & 7;
        int n = g * 16 + (l & 15);
        int k = ks * 32 + ((l >> 4) << 3) + e;
        float v = 0.f;
        if (k < 550) { int c = k / 25; v = c1w[n * 550 + k] * (1.0f / MAXV[c]); }
        W1F[idx] = f2bf(v);
    } else if (idx < 221184) {               // W2F: grp = g*36+ks, g=oc/16 (8), ks=K/32 (36); k=p*128+ic
        int j = idx - 73728;
        int grp = j >> 9, off = j & 511;
        int g = grp / 36, ks = grp - g * 36;
        int l = off >> 3, e = off & 7;
        int oc = g * 16 + (l & 15);
        int k = ks * 32 + ((l >> 4) << 3) + e;
        W2F[j] = f2bf(c2w[oc * 1152 + (k & 127) * 9 + (k >> 7)]);
    } else if (idx < 253952) {               // FCF: grp = g*4+kc, g=n/16 (16), kc=K/32 (4)
        int j = idx - 221184;
        int grp = j >> 9, off = j & 511;
        int g = grp >> 2, kc = grp & 3;
        int l = off >> 3, e = off & 7;
        int n = g * 16 + (l & 15);
        int k = kc * 32 + ((l >> 4) << 3) + e;
        FCF[j] = f2bf(fcw[n * 128 + k]);
    } else if (idx < 262144) {               // SELFF: grp = g (16), K=32 (22 real)
        int j = idx - 253952;
        int g = j >> 9, off = j & 511;
        int l = off >> 3, e = off & 7;
        int n = g * 16 + (l & 15);
        int k = ((l >> 4) << 3) + e;
        float v = (k < 22) ? sfw[n * 22 + k] * (1.0f / MAXV[k]) : 0.f;
        SELFF[j] = f2bf(v);
    } else if (idx < 278528) {               // HEADF: grp = g*16+ks, g=n/16 (2), ks=K/32 (16)
        int j = idx - 262144;
        int grp = j >> 9, off = j & 511;
        int g = grp >> 4, ks = grp & 15;
        int l = off >> 3, e = off & 7;
        int n = g * 16 + (l & 15);
        int k = ks * 32 + ((l >> 4) << 3) + e;
        float v = 0.f;
        if (n < 9) v = a0w[n * 512 + k];
        else if (n < 19) v = a1w[(n - 9) * 512 + k];
        else if (n == 19) v = vw[k];
        HEADF[j] = f2bf(v);
    } else if (idx < 279328) {               // BIAS[800]
        int j = idx - 278528;
        float v = 0.f;
        if (j < 128) v = c1b[j];
        else if (j < 256) v = c2b[j - 128];
        else if (j < 512) v = fcb[j - 256];
        else if (j < 768) v = sfb[j - 512];
        else {
            int j2 = j - 768;
            if (j2 < 9) v = a0b[j2]; else if (j2 < 19) v = a1b[j2 - 9]; else if (j2 == 19) v = vb[0];
        }
        BIAS[j] = v;
    }
}

// ---------------- K12: 4 samples/WG, 52.4KB LDS, 3 WGs/CU ----------------
// Scatter: 4 phases, versioned enc (no clears). GEMM: pipelined B-prefetch (2-deep),
// A reads via pre-swizzled bases + 128B-multiple imm offsets. Output -> h1F fragment layout.
__global__ __launch_bounds__(256, 3) void k12_kernel(
    const int* __restrict__ obs, const u16* __restrict__ W1F,
    const float* __restrict__ BIAS, u16* __restrict__ h1F, u16* __restrict__ s22g)
{
    __shared__ __align__(16) u16 A[36 * 576];     // 41,472 B
    __shared__ __align__(16) int box[2664];       // 10,656 B (repack reuses this)
    __shared__ u16 s22[128];
    const int tid = threadIdx.x, w = tid >> 6, l = tid & 63;
    const int s0 = blockIdx.x * 4;

    int tok[4][3];
    if (tid < 200) {
        #pragma unroll
        for (int p = 0; p < 4; ++p) {
            const int* tp = obs + (long)(s0 + p) * 600 + tid * 3;
            tok[p][0] = tp[0]; tok[p][1] = tp[1]; tok[p][2] = tp[2];
        }
    }

    {   // zero A + box + s22
        short8 z = {0, 0, 0, 0, 0, 0, 0, 0};
        for (int i = tid; i < 2592; i += 256) *(short8*)(A + i * 8) = z;
        int4 zz = {0, 0, 0, 0};
        for (int i = tid; i < 666; i += 256) ((int4*)box)[i] = zz;
        if (tid < 128) s22[tid] = 0;
    }
    __syncthreads();

    #pragma unroll
    for (int p = 0; p < 4; ++p) {
        int ce = 0, en = 0, va = 0, xa = 0, ya = 0, aa = 0, ok = 0;
        if (tid < 200) {
            int c = tok[p][0], a = tok[p][1], v = tok[p][2];
            c = (c == 255) ? 0 : c; a = (a == 255) ? 0 : a; v = (v == 255) ? 0 : v;
            int xs = (c >> 4) & 15, ys = c & 15;
            ok = ((unsigned)a < 22u) & (xs < 11) & (ys < 11);
            ce = a * 121 + xs * 11 + ys;
            en = ((p + 1) << 16) | (tid << 8) | (v & 255);   // versioned: stale phases always lose
            va = v; xa = xs; ya = ys; aa = a;
            if (ok) atomicMax(&box[ce], en);
        }
        __syncthreads();
        if (ok && box[ce] == en) {                            // this token won the cell
            u16 bv = f2bf((float)va);
            if (xa == 5 && ya == 5) s22[p * 32 + aa] = bv;
            int bcol = aa * 25;
            #pragma unroll
            for (int ox = 0; ox < 3; ++ox) {
                int kx = xa - 3 * ox;
                if ((unsigned)kx > 4u) continue;
                #pragma unroll
                for (int oy = 0; oy < 3; ++oy) {
                    int ky = ya - 3 * oy;
                    if ((unsigned)ky > 4u) continue;
                    int row = p * 9 + ox * 3 + oy;
                    int byte = ((row * 576 + bcol + kx * 5 + ky) << 1) ^ ((row & 7) << 4);
                    *(u16*)((char*)A + byte) = bv;
                }
            }
        }
        __syncthreads();
    }
    if (tid < 128) s22g[s0 * 32 + tid] = s22[tid];

    // ---- GEMM [48(36) x 576] x [576 x 32/wave]: pipelined, setprio'd ----
    int Aoff[3][2];
    #pragma unroll
    for (int mt = 0; mt < 3; ++mt) {
        int row = mt * 16 + (l & 15);
        row = row < 36 ? row : 35;
        int koff = (l >> 4) << 3;
        Aoff[mt][0] = ((row * 576 + koff) << 1) ^ ((row & 7) << 4);
        Aoff[mt][1] = ((row * 576 + 32 + koff) << 1) ^ ((row & 7) << 4);
    }
    const u16* Wp0 = W1F + ((w * 2 + 0) * 18 << 9) + l * 8;
    const u16* Wp1 = W1F + ((w * 2 + 1) * 18 << 9) + l * 8;

    f32x4 acc[3][2];
    const f32x4 fz = {0.f, 0.f, 0.f, 0.f};
    #pragma unroll
    for (int i = 0; i < 3; ++i) { acc[i][0] = fz; acc[i][1] = fz; }

    short8 cb0 = *(const short8*)(Wp0);
    short8 cb1 = *(const short8*)(Wp1);
    short8 nb0 = *(const short8*)(Wp0 + 512);
    short8 nb1 = *(const short8*)(Wp1 + 512);
    __builtin_amdgcn_s_setprio(1);
    #pragma unroll
    for (int ks = 0; ks < 18; ++ks) {
        short8 t0 = cb0, t1 = cb1;
        if (ks < 16) {
            t0 = *(const short8*)(Wp0 + (ks + 2) * 512);
            t1 = *(const short8*)(Wp1 + (ks + 2) * 512);
        }
        short8 a0 = *(const short8*)((const char*)A + Aoff[0][ks & 1] + (ks >> 1) * 128);
        short8 a1 = *(const short8*)((const char*)A + Aoff[1][ks & 1] + (ks >> 1) * 128);
        short8 a2 = *(const short8*)((const char*)A + Aoff[2][ks & 1] + (ks >> 1) * 128);
        acc[0][0] = MFMA16(a0, cb0, acc[0][0]);
        acc[0][1] = MFMA16(a0, cb1, acc[0][1]);
        acc[1][0] = MFMA16(a1, cb0, acc[1][0]);
        acc[1][1] = MFMA16(a1, cb1, acc[1][1]);
        acc[2][0] = MFMA16(a2, cb0, acc[2][0]);
        acc[2][1] = MFMA16(a2, cb1, acc[2][1]);
        cb0 = nb0; cb1 = nb1; nb0 = t0; nb1 = t1;
    }
    __builtin_amdgcn_s_setprio(0);

    // ---- repack into box region (free), then coalesced h1F fragment store ----
    u16* R = (u16*)box;                        // 4608 u16: R[(ks*16 + hif*4 + ds)*8 + ef]
    #pragma unroll
    for (int mt = 0; mt < 3; ++mt) {
        #pragma unroll
        for (int nt = 0; nt < 2; ++nt) {
            int col = w * 32 + nt * 16 + (l & 15);
            float bias = BIAS[col];
            int hif = nt * 2 + ((l & 15) >> 3);
            int ef = l & 7;
            #pragma unroll
            for (int r = 0; r < 4; ++r) {
                int row = mt * 16 + ((l >> 4) << 2) + r;
                if (row < 36) {
                    int ds = row / 9;
                    int pos = row - ds * 9;
                    int ks = pos * 4 + w;
                    float v = acc[mt][nt][r] + bias;
                    v = v > 0.f ? v : 0.f;
                    R[(ks * 16 + hif * 4 + ds) * 8 + ef] = f2bf(v);
                }
            }
        }
    }
    __syncthreads();
    {
        const long Cbase = (long)(s0 >> 4) * 18432 + (s0 & 15) * 8;
        #pragma unroll
        for (int q = 0; q < 3; ++q) {
            int slot = tid + q * 256;
            if (slot < 576) {
                int ks = slot >> 4, lf = slot & 15;
                *(short8*)(h1F + Cbase + ks * 512 + (lf >> 2) * 128 + (lf & 3) * 8) =
                    *(const short8*)(R + slot * 8);
            }
        }
    }
}

// ---------------- K3: 32 samples/WG, frag-direct loads, 2 barriers, 42KB LDS ----------------
__global__ __launch_bounds__(256, 2) void k3_kernel(
    const u16* __restrict__ h1F, const u16* __restrict__ s22g,
    const u16* __restrict__ W2F, const u16* __restrict__ FCF,
    const u16* __restrict__ SELFF, const u16* __restrict__ HEADF,
    const float* __restrict__ BIAS, float* __restrict__ out, int B)
{
    __shared__ __align__(16) u16 A3[32 * 136];     //  8,704 B
    __shared__ __align__(16) u16 HID[32 * 520];    // 33,280 B
    const int tid = threadIdx.x, w = tid >> 6, l = tid & 63;
    const int s0 = blockIdx.x * 32;
    const int sb = blockIdx.x * 2;
    const float* c2b = BIAS + 128;
    const float* fcb = BIAS + 256;
    const float* sfb = BIAS + 512;
    const float* hdb = BIAS + 768;
    const f32x4 fz = {0.f, 0.f, 0.f, 0.f};

    // ---- conv2: M=32 (2 frag tiles), N=128 (32/wave), K=1152 (36 slots), barrier-free ----
    f32x4 acc[2][2];
    acc[0][0] = fz; acc[0][1] = fz; acc[1][0] = fz; acc[1][1] = fz;
    const u16* A0p = h1F + (long)(sb + 0) * 18432 + l * 8;
    const u16* A1p = h1F + (long)(sb + 1) * 18432 + l * 8;
    const u16* B0p = W2F + ((w * 2 + 0) * 36 << 9) + l * 8;
    const u16* B1p = W2F + ((w * 2 + 1) * 36 << 9) + l * 8;

    short8 ca0 = *(const short8*)(A0p), ca1 = *(const short8*)(A1p);
    short8 cb0 = *(const short8*)(B0p), cb1 = *(const short8*)(B1p);
    short8 na0 = *(const short8*)(A0p + 512), na1 = *(const short8*)(A1p + 512);
    short8 nb0 = *(const short8*)(B0p + 512), nb1 = *(const short8*)(B1p + 512);
    __builtin_amdgcn_s_setprio(1);
    #pragma unroll
    for (int ks = 0; ks < 36; ++ks) {
        short8 t0 = ca0, t1 = ca1, t2 = cb0, t3 = cb1;
        if (ks < 34) {
            t0 = *(const short8*)(A0p + (ks + 2) * 512);
            t1 = *(const short8*)(A1p + (ks + 2) * 512);
            t2 = *(const short8*)(B0p + (ks + 2) * 512);
            t3 = *(const short8*)(B1p + (ks + 2) * 512);
        }
        acc[0][0] = MFMA16(ca0, cb0, acc[0][0]);
        acc[0][1] = MFMA16(ca0, cb1, acc[0][1]);
        acc[1][0] = MFMA16(ca1, cb0, acc[1][0]);
        acc[1][1] = MFMA16(ca1, cb1, acc[1][1]);
        ca0 = na0; ca1 = na1; cb0 = nb0; cb1 = nb1;
        na0 = t0; na1 = t1; nb0 = t2; nb1 = t3;
    }
    __builtin_amdgcn_s_setprio(0);
    {
        #pragma unroll
        for (int mt = 0; mt < 2; ++mt)
            #pragma unroll
            for (int nt = 0; nt < 2; ++nt) {
                int col = w * 32 + nt * 16 + (l & 15);
                float bias = c2b[col];
                #pragma unroll
                for (int r = 0; r < 4; ++r) {
                    int row = mt * 16 + ((l >> 4) << 2) + r;
                    float v = acc[mt][nt][r] + bias; v = v > 0.f ? v : 0.f;
                    A3[row * 136 + col] = f2bf(v);
                }
            }
    }
    __syncthreads();                                   // barrier 1

    // ---- fc: A3(LDS) x FCF-frags -> HID cols 256..511 ----
    f32x4 acc8[2][4];
    #pragma unroll
    for (int i = 0; i < 2; ++i)
        #pragma unroll
        for (int j = 0; j < 4; ++j) acc8[i][j] = fz;
    #pragma unroll
    for (int kc = 0; kc < 4; ++kc) {
        short8 bf[4];
        #pragma unroll
        for (int nt = 0; nt < 4; ++nt)
            bf[nt] = *(const short8*)(FCF + (((w * 4 + nt) * 4 + kc) << 9) + l * 8);
        #pragma unroll
        for (int mt = 0; mt < 2; ++mt) {
            short8 a = *(const short8*)(A3 + (mt * 16 + (l & 15)) * 136 + kc * 32 + ((l >> 4) << 3));
            #pragma unroll
            for (int nt = 0; nt < 4; ++nt) acc8[mt][nt] = MFMA16(a, bf[nt], acc8[mt][nt]);
        }
    }
    {
        #pragma unroll
        for (int mt = 0; mt < 2; ++mt)
            #pragma unroll
            for (int nt = 0; nt < 4; ++nt) {
                int col = w * 64 + nt * 16 + (l & 15);
                float bias = fcb[col];
                #pragma unroll
                for (int r = 0; r < 4; ++r) {
                    int row = mt * 16 + ((l >> 4) << 2) + r;
                    float v = acc8[mt][nt][r] + bias; v = v > 0.f ? v : 0.f;
                    HID[row * 520 + 256 + col] = f2bf(v);
                }
            }
    }

    // ---- self: s22g-frags x SELFF-frags -> HID cols 0..255 (no LDS staging) ----
    {
        f32x4 acc9[2][4];
        #pragma unroll
        for (int i = 0; i < 2; ++i)
            #pragma unroll
            for (int j = 0; j < 4; ++j) acc9[i][j] = fz;
        short8 bs[4];
        #pragma unroll
        for (int nt = 0; nt < 4; ++nt)
            bs[nt] = *(const short8*)(SELFF + ((w * 4 + nt) << 9) + l * 8);
        #pragma unroll
        for (int mt = 0; mt < 2; ++mt) {
            short8 a = *(const short8*)(s22g + (s0 + mt * 16 + (l & 15)) * 32 + ((l >> 4) << 3));
            #pragma unroll
            for (int nt = 0; nt < 4; ++nt) acc9[mt][nt] = MFMA16(a, bs[nt], acc9[mt][nt]);
        }
        #pragma unroll
        for (int mt = 0; mt < 2; ++mt)
            #pragma unroll
            for (int nt = 0; nt < 4; ++nt) {
                int col = w * 64 + nt * 16 + (l & 15);
                float bias = sfb[col];
                #pragma unroll
                for (int r = 0; r < 4; ++r) {
                    int row = mt * 16 + ((l >> 4) << 2) + r;
                    float v = acc9[mt][nt][r] + bias; v = v > 0.f ? v : 0.f;
                    HID[row * 520 + col] = f2bf(v);
                }
            }
    }
    __syncthreads();                                   // barrier 2

    // ---- heads: HID(LDS) x HEADF-frags, 16 K-slots, barrier-free ----
    f32x4 hacc = fz;
    const int rt = w & 1, ct = w >> 1;
    #pragma unroll
    for (int ks = 0; ks < 16; ++ks) {
        short8 a = *(const short8*)(HID + (rt * 16 + (l & 15)) * 520 + ks * 32 + ((l >> 4) << 3));
        short8 b = *(const short8*)(HEADF + ((ct * 16 + ks) << 9) + l * 8);
        hacc = MFMA16(a, b, hacc);
    }
    #pragma unroll
    for (int r = 0; r < 4; ++r) {
        int srow = s0 + rt * 16 + ((l >> 4) << 2) + r;
        int col = ct * 16 + (l & 15);
        float v = hacc[r] + hdb[col];
        if (col < 9) out[(long)srow * 9 + col] = v;
        else if (col < 19) out[(long)B * 9 + (long)srow * 10 + (col - 9)] = v;
        else if (col == 19) out[(long)B * 19 + srow] = v;
    }
}

extern "C" void kernel_launch(void* const* d_in, const int* in_sizes, int n_in,
                              void* d_out, int out_size, void* d_ws, size_t ws_size,
                              hipStream_t stream)
{
    const int*   obs = (const int*)d_in[0];
    const float* c1w = (const float*)d_in[1];
    const float* c1b = (const float*)d_in[2];
    const float* c2w = (const float*)d_in[3];
    const float* c2b = (const float*)d_in[4];
    const float* fcw = (const float*)d_in[5];
    const float* fcb = (const float*)d_in[6];
    const float* sfw = (const float*)d_in[7];
    const float* sfb = (const float*)d_in[8];
    const float* a0w = (const float*)d_in[9];
    const float* a0b = (const float*)d_in[10];
    const float* a1w = (const float*)d_in[11];
    const float* a1b = (const float*)d_in[12];
    const float* vw  = (const float*)d_in[13];
    const float* vb  = (const float*)d_in[14];
    const int B = in_sizes[0] / 600;   // 16384

    char* ws = (char*)d_ws;
    u16*   W1F   = (u16*)(ws + 0);
    u16*   W2F   = (u16*)(ws + 147456);
    u16*   FCF   = (u16*)(ws + 442368);
    u16*   SELFF = (u16*)(ws + 507904);
    u16*   HEADF = (u16*)(ws + 524288);
    float* BIAS  = (float*)(ws + 557056);
    u16*   s22g  = (u16*)(ws + 560256);
    u16*   h1F   = (u16*)(ws + 560256 + (size_t)B * 64);

    prep_kernel<<<1092, 256, 0, stream>>>(c1w, c1b, c2w, c2b, fcw, fcb, sfw, sfb,
                                          a0w, a0b, a1w, a1b, vw, vb,
                                          W1F, W2F, FCF, SELFF, HEADF, BIAS);
    k12_kernel<<<B / 4, 256, 0, stream>>>(obs, W1F, BIAS, h1F, s22g);
    k3_kernel<<<B / 32, 256, 0, stream>>>(h1F, s22g, W2F, FCF, SELFF, HEADF, BIAS,
                                          (float*)d_out, B);
}